// Round 15
// baseline (99.230 us; speedup 1.0000x reference)
//
#include <hip/hip_runtime.h>
#include <cstdint>

#define BDIM  2
#define TSEQ  2048
#define CDIM  1024
#define NHEAD 16
#define HDIM  64
#define C3    3072

typedef __attribute__((ext_vector_type(8))) short short8_t;
typedef __attribute__((ext_vector_type(4))) short short4_t;
typedef __attribute__((ext_vector_type(4))) float f32x4;

static __device__ __forceinline__ unsigned short f2bf(float f) {
  union { float f; unsigned u; } v; v.f = f;
  unsigned r = v.u + 0x7FFFu + ((v.u >> 16) & 1u);   // RNE
  return (unsigned short)(r >> 16);
}
// pack 2 f32 -> 2 bf16 in one u32 (v_cvt_pk_bf16_f32, RNE)
static __device__ __forceinline__ unsigned cvtpk_bf16(float lo, float hi) {
  unsigned r;
  asm("v_cvt_pk_bf16_f32 %0, %1, %2" : "=v"(r) : "v"(lo), "v"(hi));
  return r;
}
// async global->LDS, 16B per lane. LDS dest = wave-uniform base + lane*16.
static __device__ __forceinline__ void g2lds16(const unsigned short* g,
                                               unsigned short* l) {
  __builtin_amdgcn_global_load_lds(
      (const __attribute__((address_space(1))) void*)g,
      (__attribute__((address_space(3))) void*)l, 16, 0, 0);
}

// [rows][64] bf16 tiles, 16B chunks 0..7 (chunk=elem>>3), chunk ^= row&7.
__device__ __forceinline__ int kk_idx(int row, int chunk) {
  return row * 64 + (((chunk ^ (row & 7)) & 7) << 3);
}
// attn V^T tile: [64 d][64 kv] bf16, chunks 0..7 (kv>>3),
// chunk ^= (d&7) ^ ((d>>3)&7)
__device__ __forceinline__ int vv_idx(int d, int chunk) {
  return d * 64 + (((chunk ^ (d & 7) ^ ((d >> 3) & 7)) & 7) << 3);
}

// ---------------------------------------------------------------------------
// Merged fp32 -> bf16 conversion for x, Wqkv, Wproj (outputs contiguous).
__global__ __launch_bounds__(256) void f32_to_bf16_3(
    const float* __restrict__ x, const float* __restrict__ wq,
    const float* __restrict__ wp, unsigned short* __restrict__ outb,
    int n1, int n2, int n3)
{
  const int i = blockIdx.x * 256 + threadIdx.x;
  const float* src; unsigned short* dst; int j;
  if (i < n1)            { src = x;  dst = outb;                        j = i; }
  else if (i < n1 + n2)  { src = wq; dst = outb + (size_t)n1 * 4;       j = i - n1; }
  else if (i < n1+n2+n3) { src = wp; dst = outb + (size_t)(n1+n2) * 4;  j = i - n1 - n2; }
  else return;
  const float4 v = ((const float4*)src)[j];
  const unsigned lo = (unsigned)f2bf(v.x) | ((unsigned)f2bf(v.y) << 16);
  const unsigned hi = (unsigned)f2bf(v.z) | ((unsigned)f2bf(v.w) << 16);
  ((uint2*)dst)[j] = make_uint2(lo, hi);
}

// ---------------------------------------------------------------------------
// C[m][n] = sum_k A[m][k]*B[n][k] + bias[n]; A,B bf16, bias fp32.
// bf16 MFMA 16x16x32, BM=128, BN=FJ*32, BK=64, 4 waves (2x2), 4xFJ frags.
// Staging via global_load_lds (linear LDS dest, pre-swizzled global source).
// ---------------------------------------------------------------------------
template <int FJ, bool OUT_BF16, int MWPE>
__global__ __launch_bounds__(256, MWPE) void gemm_bt_mfma(
    const unsigned short* __restrict__ A, const unsigned short* __restrict__ B,
    const float* __restrict__ bias, void* __restrict__ Cv,
    int M, int N, int K)
{
  __shared__ unsigned short As[128 * 64];
  __shared__ unsigned short Bs[FJ * 32 * 64];

  const int tid  = threadIdx.x;
  const int lane = tid & 63;
  const int wv   = tid >> 6;
  const int wr   = wv >> 1, wc = wv & 1;
  const int l15  = lane & 15, g = lane >> 4;
  const int bn = blockIdx.x, bm = blockIdx.y;

  const int srow = tid >> 3;                      // 0..31 (call adds c*32)
  const int chg  = (tid & 7) ^ (srow & 7);        // pre-swizzled source chunk
  const unsigned short* Ab = A + (size_t)(bm * 128 + srow) * K + chg * 8;
  const unsigned short* Bb = B + (size_t)(bn * (FJ * 32) + srow) * K + chg * 8;

  f32x4 acc[4][FJ];
#pragma unroll
  for (int i = 0; i < 4; ++i)
#pragma unroll
    for (int j = 0; j < FJ; ++j) acc[i][j] = (f32x4){0.f, 0.f, 0.f, 0.f};

  for (int k0 = 0; k0 < K; k0 += 64) {
    __syncthreads();            // prev iter's readers done
#pragma unroll
    for (int c = 0; c < 4; ++c)
      g2lds16(Ab + (size_t)(c * 32) * K + k0, &As[c * 2048 + wv * 512]);
#pragma unroll
    for (int c = 0; c < FJ; ++c)
      g2lds16(Bb + (size_t)(c * 32) * K + k0, &Bs[c * 2048 + wv * 512]);
    __syncthreads();            // implicit vmcnt(0) drains the DMA

#pragma unroll
    for (int kk = 0; kk < 2; ++kk) {
      short8_t af[4], bf[FJ];
#pragma unroll
      for (int i = 0; i < 4; ++i)
        af[i] = *(const short8_t*)&As[kk_idx(wr * 64 + i * 16 + l15, kk * 4 + g)];
#pragma unroll
      for (int j = 0; j < FJ; ++j)
        bf[j] = *(const short8_t*)&Bs[kk_idx(wc * (FJ * 16) + j * 16 + l15, kk * 4 + g)];
#pragma unroll
      for (int i = 0; i < 4; ++i)
#pragma unroll
        for (int j = 0; j < FJ; ++j)
          acc[i][j] = __builtin_amdgcn_mfma_f32_16x16x32_bf16(af[i], bf[j], acc[i][j], 0, 0, 0);
    }
  }

#pragma unroll
  for (int j = 0; j < FJ; ++j) {
    const int col = bn * (FJ * 32) + wc * (FJ * 16) + j * 16 + l15;
    const float bj = bias[col];
#pragma unroll
    for (int i = 0; i < 4; ++i) {
#pragma unroll
      for (int r = 0; r < 4; ++r) {
        const int row = bm * 128 + wr * 64 + i * 16 + g * 4 + r;
        const float v = acc[i][j][r] + bj;
        if (OUT_BF16) ((unsigned short*)Cv)[(size_t)row * N + col] = f2bf(v);
        else          ((float*)Cv)[(size_t)row * N + col] = v;
      }
    }
  }
}

// ---------------------------------------------------------------------------
// Causal flash attention, bf16 MFMA 16x16x32, swapped QK^T, split-KV.
// LDS-BW-optimized decomposition: block = 256 thr / 4 waves, 64 q-rows.
// wave -> (qs=wv&1: 32-q subtile, kvh=wv>>1: 32-kv half). Each wave holds
// TWO Q frags (qm=0,1) so every kf/vf LDS read is register-reused for 32 q
// rows: per-CU LDS bytes/step drop ~1.6x vs the 16q/wave layout (measured
// DS-pipe-saturated at 96%). Blocks pair q-tiles (x,31-x) -> 512 balanced
// blocks, 2/CU. Fast path below diagonal + masked tail; speculative exp
// with defer-max; kv halves merge per phase in LDS. XCD-grouped grid.
// VGPR budget: <=128 keeps 16 waves/CU possible; even >128 keeps our
// 8 resident waves (2 blocks x 4) -> no occupancy cliff by construction.
// ---------------------------------------------------------------------------
__global__ __launch_bounds__(256, 2) void attn_mfma(
    const unsigned short* __restrict__ qkv, unsigned short* __restrict__ yb)
{
  __shared__ unsigned short SM[21504];  // K 2x4096 | V 2x4096 | P 4x1280
  unsigned short* Ks = SM;
  unsigned short* Vt = SM + 8192;
  unsigned short* Ps = SM + 16384;

  const int tid  = threadIdx.x;
  const int lane = tid & 63;
  const int wv   = tid >> 6;          // 0..3
  const int qs   = wv & 1;            // 32-row q-subtile within block
  const int kvh  = wv >> 1;           // kv half (0: kv 0..31, 1: 32..63)
  const int l15  = lane & 15, g = lane >> 4;

  // XCD grouping: bits[2:0]+bit[8:7] pick (b,h) group; bits[6:3] pick x.
  const int nfl = blockIdx.x;
  const int x   = (nfl >> 3) & 15;
  const int grp = (nfl & 7) | ((nfl >> 7) << 3);
  const int h = grp & 15, b = grp >> 4;

  const unsigned short* kbase = qkv + (size_t)(b * TSEQ) * C3 + CDIM + h * HDIM;
  const unsigned short* vbase = kbase + CDIM;
  unsigned short* Pw = &Ps[wv * 1280];     // [32 q][40]

  const float SC2 = 0.18033688011112042f;   // log2(e)/8
  const float THR = 11.5415603f;            // 8*log2(e)

  // staging map (256 threads): K row skv=tid>>2, chunks sa,sa+1 (2 b128)
  const int skv = tid >> 2;
  const int sa  = (tid & 3) * 2;
  const int kw0 = kk_idx(skv, sa + 0);
  const int kw1 = kk_idx(skv, sa + 1);
  // V: kv pair vs=tid>>3, d-chunk va=tid&7; 8 packed b32 writes
  const int vs = tid >> 3, va = tid & 7;
  int vwo[8];
#pragma unroll
  for (int j = 0; j < 8; ++j)
    vwo[j] = vv_idx(va * 8 + j, vs >> 2) + ((2 * vs) & 7);

  int tg = 0;   // staged-tile parity, continuous across phases

  for (int ph = 0; ph < 2; ++ph) {
    const int qt   = ph ? (31 - x) : x;       // 64-row q-tile id
    const int wq0  = qt * 64 + qs * 32;       // wave's first q row (of 32)

    // Q fragments (B-operand: col=q=l15, k=kk*32+g*8), qm in {0,1}
    short8_t qf[2][2];
#pragma unroll
    for (int qm = 0; qm < 2; ++qm)
#pragma unroll
      for (int kk = 0; kk < 2; ++kk)
        qf[qm][kk] = *(const short8_t*)(qkv +
            (size_t)(b * TSEQ + wq0 + qm * 16 + l15) * C3 + h * HDIM + kk * 32 + g * 8);

    f32x4 O[2][4];
#pragma unroll
    for (int qm = 0; qm < 2; ++qm)
#pragma unroll
      for (int n = 0; n < 4; ++n) O[qm][n] = (f32x4){0.f, 0.f, 0.f, 0.f};
    float Mr[2] = {0.0f, 0.0f}, Lr[2] = {0.f, 0.f};

    // prefetch tile 0 into registers
    const unsigned short* kptr  = kbase + (size_t)skv * C3 + sa * 8;
    const unsigned short* vptr0 = vbase + (size_t)(2 * vs) * C3 + va * 8;
    const unsigned short* vptr1 = vptr0 + C3;
    short8_t pk0 = *(const short8_t*)(kptr);
    short8_t pk1 = *(const short8_t*)(kptr + 8);
    short8_t pv0 = *(const short8_t*)(vptr0);
    short8_t pv1 = *(const short8_t*)(vptr1);

    // ---- main loop: tiles fully below the diagonal for EVERY wave ----
    for (int t = 0; t < qt; ++t) {
      const int par = tg & 1;
      unsigned short* Kc = &Ks[par * 4096];
      unsigned short* Vc = &Vt[par * 4096];
      tg++;
      *(short8_t*)&Kc[kw0] = pk0;
      *(short8_t*)&Kc[kw1] = pk1;
      {
        const unsigned short* e0 = (const unsigned short*)&pv0;
        const unsigned short* e1 = (const unsigned short*)&pv1;
#pragma unroll
        for (int j = 0; j < 8; ++j)
          *(unsigned*)&Vc[vwo[j]] = (unsigned)e0[j] | ((unsigned)e1[j] << 16);
      }
      __syncthreads();
      // next tile always exists here (t+1 <= qt)
      kptr  += (size_t)64 * C3;
      vptr0 += (size_t)64 * C3;
      vptr1 += (size_t)64 * C3;
      pk0 = *(const short8_t*)(kptr); pk1 = *(const short8_t*)(kptr + 8);
      pv0 = *(const short8_t*)(vptr0); pv1 = *(const short8_t*)(vptr1);

      // S^T = K Q^T  (D-layout: row(kv)=g*4+r, col(q)=l15); kf reused 2 qm
      f32x4 s[2][2];   // [n][qm]
#pragma unroll
      for (int n = 0; n < 2; ++n)
#pragma unroll
        for (int qm = 0; qm < 2; ++qm) s[n][qm] = (f32x4){0.f, 0.f, 0.f, 0.f};
      __builtin_amdgcn_s_setprio(1);
#pragma unroll
      for (int n = 0; n < 2; ++n) {
#pragma unroll
        for (int kk = 0; kk < 2; ++kk) {
          const short8_t kf =
              *(const short8_t*)&Kc[kk_idx(kvh * 32 + n * 16 + l15, kk * 4 + g)];
#pragma unroll
          for (int qm = 0; qm < 2; ++qm)
            s[n][qm] = __builtin_amdgcn_mfma_f32_16x16x32_bf16(kf, qf[qm][kk], s[n][qm], 0, 0, 0);
        }
      }
      __builtin_amdgcn_s_setprio(0);

      // no mask; raw max; scale fused into exp (speculative vs Mr)
      float mt[2] = {-3.0e38f, -3.0e38f}, rs[2] = {0.f, 0.f};
#pragma unroll
      for (int qm = 0; qm < 2; ++qm) {
#pragma unroll
        for (int n = 0; n < 2; ++n)
#pragma unroll
          for (int r = 0; r < 4; ++r) mt[qm] = fmaxf(mt[qm], s[n][qm][r]);
#pragma unroll
        for (int n = 0; n < 2; ++n)
#pragma unroll
          for (int r = 0; r < 4; ++r) {
            const float p = __builtin_amdgcn_exp2f(fmaf(s[n][qm][r], SC2, -Mr[qm]));
            s[n][qm][r] = p;
            rs[qm] += p;
          }
        // pack & store P (row q = qm*16+l15)
#pragma unroll
        for (int n = 0; n < 2; ++n) {
          const unsigned u0 = cvtpk_bf16(s[n][qm][0], s[n][qm][1]);
          const unsigned u1 = cvtpk_bf16(s[n][qm][2], s[n][qm][3]);
          *(uint2*)&Pw[(qm * 16 + l15) * 40 + n * 16 + (g << 2)] = make_uint2(u0, u1);
        }
        mt[qm] *= SC2;
      }
      // lane-local defer-max test (shuffles only inside the rare branch)
      if (__any((mt[0] > Mr[0] + THR) || (mt[1] > Mr[1] + THR))) {
#pragma unroll
        for (int qm = 0; qm < 2; ++qm) {
          float mq = mt[qm];
          mq = fmaxf(mq, __shfl_xor(mq, 16));
          mq = fmaxf(mq, __shfl_xor(mq, 32));
          const float nm = fmaxf(Mr[qm], mq);
          const float al = __builtin_amdgcn_exp2f(Mr[qm] - nm);
          Lr[qm] *= al;
          rs[qm] *= al;
          float alq[4];
#pragma unroll
          for (int r = 0; r < 4; ++r) alq[r] = __shfl(al, (g << 2) + r);
#pragma unroll
          for (int n = 0; n < 4; ++n)
#pragma unroll
            for (int r = 0; r < 4; ++r) O[qm][n][r] *= alq[r];
          Mr[qm] = nm;
#pragma unroll
          for (int n = 0; n < 2; ++n) {
#pragma unroll
            for (int r = 0; r < 4; ++r) s[n][qm][r] *= al;
            const unsigned u0 = cvtpk_bf16(s[n][qm][0], s[n][qm][1]);
            const unsigned u1 = cvtpk_bf16(s[n][qm][2], s[n][qm][3]);
            *(uint2*)&Pw[(qm * 16 + l15) * 40 + n * 16 + (g << 2)] = make_uint2(u0, u1);
          }
        }
      }

      // PV: A = P[qm] (row=q, k=g*8+j), B = V^T; vf reused for both qm
      const short8_t pf0 = *(const short8_t*)&Pw[(0 * 16 + l15) * 40 + g * 8];
      const short8_t pf1 = *(const short8_t*)&Pw[(1 * 16 + l15) * 40 + g * 8];
      __builtin_amdgcn_s_setprio(1);
#pragma unroll
      for (int n = 0; n < 4; ++n) {
        const short8_t vf = *(const short8_t*)&Vc[vv_idx(n * 16 + l15, kvh * 4 + g)];
        O[0][n] = __builtin_amdgcn_mfma_f32_16x16x32_bf16(pf0, vf, O[0][n], 0, 0, 0);
        O[1][n] = __builtin_amdgcn_mfma_f32_16x16x32_bf16(pf1, vf, O[1][n], 0, 0, 0);
      }
      __builtin_amdgcn_s_setprio(0);

#pragma unroll
      for (int qm = 0; qm < 2; ++qm) {
        rs[qm] += __shfl_xor(rs[qm], 16);
        rs[qm] += __shfl_xor(rs[qm], 32);
        Lr[qm] += rs[qm];
      }
    }

    // ---- final tile t = qt: contains the diagonal; masked body ----
    {
      const int par = tg & 1;
      unsigned short* Kc = &Ks[par * 4096];
      unsigned short* Vc = &Vt[par * 4096];
      tg++;
      *(short8_t*)&Kc[kw0] = pk0;
      *(short8_t*)&Kc[kw1] = pk1;
      {
        const unsigned short* e0 = (const unsigned short*)&pv0;
        const unsigned short* e1 = (const unsigned short*)&pv1;
#pragma unroll
        for (int j = 0; j < 8; ++j)
          *(unsigned*)&Vc[vwo[j]] = (unsigned)e0[j] | ((unsigned)e1[j] << 16);
      }
      __syncthreads();
      const int kvw0 = qt * 64 + kvh * 32;

#pragma unroll
      for (int qm = 0; qm < 2; ++qm) {
        const int wq0m = wq0 + qm * 16;       // this qm's first q row
        const int q_hi = wq0m + 15;
        const int qg   = wq0m + l15;          // this lane's q row
        if (kvw0 > q_hi) continue;            // wave-uniform per qm
        const int nl = (q_hi - kvw0) >> 4;
        const int nlim = (nl > 1) ? 1 : nl;

        f32x4 s[2];
#pragma unroll
        for (int n = 0; n < 2; ++n) s[n] = (f32x4){0.f, 0.f, 0.f, 0.f};
        __builtin_amdgcn_s_setprio(1);
#pragma unroll
        for (int n = 0; n < 2; ++n) {
          if (n <= nlim) {
#pragma unroll
            for (int kk = 0; kk < 2; ++kk) {
              const short8_t kf =
                  *(const short8_t*)&Kc[kk_idx(kvh * 32 + n * 16 + l15, kk * 4 + g)];
              s[n] = __builtin_amdgcn_mfma_f32_16x16x32_bf16(kf, qf[qm][kk], s[n], 0, 0, 0);
            }
          }
        }
        __builtin_amdgcn_s_setprio(0);

        float mt = -3.0e38f;
#pragma unroll
        for (int n = 0; n < 2; ++n) {
          if (n <= nlim) {
            const int kvb = kvw0 + n * 16 + g * 4;
            const bool needmask = (kvw0 + n * 16 + 15 > wq0m);
#pragma unroll
            for (int r = 0; r < 4; ++r) {
              float v = s[n][r] * SC2;
              if (needmask && (kvb + r > qg)) v = -3.0e38f;
              s[n][r] = v;
              mt = fmaxf(mt, v);
            }
          }
        }
        float rs = 0.f;
#pragma unroll
        for (int n = 0; n < 2; ++n) {
          if (n <= nlim) {
#pragma unroll
            for (int r = 0; r < 4; ++r) {
              const float p = __builtin_amdgcn_exp2f(s[n][r] - Mr[qm]);
              s[n][r] = p;
              rs += p;
            }
          }
          // n > nlim: s[n] stays 0 -> zero P columns (PV-safe)
        }
#pragma unroll
        for (int n = 0; n < 2; ++n) {
          const unsigned u0 = cvtpk_bf16(s[n][0], s[n][1]);
          const unsigned u1 = cvtpk_bf16(s[n][2], s[n][3]);
          *(uint2*)&Pw[(qm * 16 + l15) * 40 + n * 16 + (g << 2)] = make_uint2(u0, u1);
        }
        mt = fmaxf(mt, __shfl_xor(mt, 16));
        mt = fmaxf(mt, __shfl_xor(mt, 32));
        if (__any(mt > Mr[qm] + THR)) {
          const float nm = fmaxf(Mr[qm], mt);
          const float al = __builtin_amdgcn_exp2f(Mr[qm] - nm);
          Lr[qm] *= al;
          rs *= al;
          float alq[4];
#pragma unroll
          for (int r = 0; r < 4; ++r) alq[r] = __shfl(al, (g << 2) + r);
#pragma unroll
          for (int n = 0; n < 4; ++n)
#pragma unroll
            for (int r = 0; r < 4; ++r) O[qm][n][r] *= alq[r];
          Mr[qm] = nm;
#pragma unroll
          for (int n = 0; n < 2; ++n) {
            if (n <= nlim) {
#pragma unroll
              for (int r = 0; r < 4; ++r) s[n][r] *= al;
            }
            const unsigned u0 = cvtpk_bf16(s[n][0], s[n][1]);
            const unsigned u1 = cvtpk_bf16(s[n][2], s[n][3]);
            *(uint2*)&Pw[(qm * 16 + l15) * 40 + n * 16 + (g << 2)] = make_uint2(u0, u1);
          }
        }

        const short8_t pf = *(const short8_t*)&Pw[(qm * 16 + l15) * 40 + g * 8];
        __builtin_amdgcn_s_setprio(1);
#pragma unroll
        for (int n = 0; n < 4; ++n) {
          const short8_t vf = *(const short8_t*)&Vc[vv_idx(n * 16 + l15, kvh * 4 + g)];
          O[qm][n] = __builtin_amdgcn_mfma_f32_16x16x32_bf16(pf, vf, O[qm][n], 0, 0, 0);
        }
        __builtin_amdgcn_s_setprio(0);

        rs += __shfl_xor(rs, 16);
        rs += __shfl_xor(rs, 32);
        Lr[qm] += rs;
      }
    }

    // ---- combine kv halves: waves (qs, kvh=0) and (qs, kvh=1) ----
    __syncthreads();                       // all waves done reading K/V LDS
    {
      float* Cb = (float*)SM;              // 4*64*18 floats = 18432 B
      if (kvh == 1) {
#pragma unroll
        for (int qm = 0; qm < 2; ++qm) {
          const int slot = ((qs * 2 + qm) * 64 + lane) * 18;
#pragma unroll
          for (int n = 0; n < 4; ++n)
#pragma unroll
            for (int r = 0; r < 4; ++r) Cb[slot + n * 4 + r] = O[qm][n][r];
          Cb[slot + 16] = Mr[qm];
          Cb[slot + 17] = Lr[qm];
        }
      }
    }
    __syncthreads();
    if (kvh == 0) {
      const float* Cb = (const float*)SM;
#pragma unroll
      for (int qm = 0; qm < 2; ++qm) {
        const int slot = ((qs * 2 + qm) * 64 + lane) * 18;
        const float m2 = Cb[slot + 16], l2 = Cb[slot + 17];
        const float m  = fmaxf(Mr[qm], m2);
        const float a1 = __builtin_amdgcn_exp2f(Mr[qm] - m);
        const float a2 = __builtin_amdgcn_exp2f(m2 - m);
        const float inv = 1.0f / (Lr[qm] * a1 + l2 * a2);
        const float fa = a1 * inv, fb = a2 * inv;
        float faq[4], fbq[4];
#pragma unroll
        for (int r = 0; r < 4; ++r) {
          faq[r] = __shfl(fa, (g << 2) + r);
          fbq[r] = __shfl(fb, (g << 2) + r);
        }
#pragma unroll
        for (int n = 0; n < 4; ++n)
#pragma unroll
          for (int r = 0; r < 4; ++r) {
            const float o2 = Cb[slot + n * 4 + r];
            const size_t row = (size_t)(b * TSEQ + wq0 + qm * 16 + (g << 2) + r);
            yb[row * CDIM + h * HDIM + n * 16 + l15] =
                f2bf(O[qm][n][r] * faq[r] + o2 * fbq[r]);
          }
      }
    }
    __syncthreads();                       // protect Cb before next staging
  }
}

// ---------------------------------------------------------------------------
extern "C" void kernel_launch(void* const* d_in, const int* in_sizes, int n_in,
                              void* d_out, int out_size, void* d_ws, size_t ws_size,
                              hipStream_t stream)
{
  const float* x     = (const float*)d_in[0];   // [B,T,C] fp32
  const float* Wqkv  = (const float*)d_in[1];   // [3C,C]  fp32
  const float* bqkv  = (const float*)d_in[2];   // [3C]
  const float* Wproj = (const float*)d_in[3];   // [C,C]
  const float* bproj = (const float*)d_in[4];   // [C]
  float* out = (float*)d_out;                   // [B,T,C] fp32

  const int M = BDIM * TSEQ;                    // 4096
  unsigned short* qkv = (unsigned short*)d_ws;          // M x 3C
  unsigned short* yb  = qkv + (size_t)M * C3;           // M x C
  unsigned short* xb  = yb  + (size_t)M * CDIM;         // M x C   (contig with
  unsigned short* wqb = xb  + (size_t)M * CDIM;         // 3C x C   wqb, wpb)
  unsigned short* wpb = wqb + (size_t)C3 * CDIM;        // C x C

  // 0) fp32 -> bf16 pre-conversion (RNE), single merged kernel
  const int n1 = M * CDIM / 4, n2 = C3 * CDIM / 4, n3 = CDIM * CDIM / 4;
  f32_to_bf16_3<<<(n1 + n2 + n3 + 255) / 256, 256, 0, stream>>>(
      x, Wqkv, Wproj, xb, n1, n2, n3);

  // 1) qkv = bf16(x @ Wqkv^T + bqkv)   (BN=128, 768 blocks = 3/CU)
  gemm_bt_mfma<4, true, 3><<<dim3(C3 / 128, M / 128), 256, 0, stream>>>(
      xb, wqb, bqkv, (void*)qkv, M, C3, CDIM);

  // 2) causal attention -> yb (bf16)
  attn_mfma<<<dim3(512, 1, 1), 256, 0, stream>>>(qkv, yb);

  // 3) out = yb @ Wproj^T + bproj (fp32 out)  (BN=64 -> 512 blocks, 2/CU)
  gemm_bt_mfma<2, false, 2><<<dim3(CDIM / 64, M / 128), 256, 0, stream>>>(
      yb, wpb, bproj, (void*)out, M, CDIM, CDIM);
}

// Round 17
// 97.161 us; speedup vs baseline: 1.0213x; 1.0213x over previous
//
#include <hip/hip_runtime.h>
#include <cstdint>

#define BDIM  2
#define TSEQ  2048
#define CDIM  1024
#define NHEAD 16
#define HDIM  64
#define C3    3072

typedef __attribute__((ext_vector_type(8))) short short8_t;
typedef __attribute__((ext_vector_type(4))) short short4_t;
typedef __attribute__((ext_vector_type(4))) float f32x4;

static __device__ __forceinline__ unsigned short f2bf(float f) {
  union { float f; unsigned u; } v; v.f = f;
  unsigned r = v.u + 0x7FFFu + ((v.u >> 16) & 1u);   // RNE
  return (unsigned short)(r >> 16);
}
// pack 2 f32 -> 2 bf16 in one u32 (v_cvt_pk_bf16_f32, RNE)
static __device__ __forceinline__ unsigned cvtpk_bf16(float lo, float hi) {
  unsigned r;
  asm("v_cvt_pk_bf16_f32 %0, %1, %2" : "=v"(r) : "v"(lo), "v"(hi));
  return r;
}
// async global->LDS, 16B per lane. LDS dest = wave-uniform base + lane*16.
static __device__ __forceinline__ void g2lds16(const unsigned short* g,
                                               unsigned short* l) {
  __builtin_amdgcn_global_load_lds(
      (const __attribute__((address_space(1))) void*)g,
      (__attribute__((address_space(3))) void*)l, 16, 0, 0);
}
// lgkmcnt-only barrier: the attn staging protected by this barrier is
// ds_write-only; skipping __syncthreads()'s implicit vmcnt(0) drain lets
// the register-private K/V global prefetch loads stay in flight across the
// barrier. (Correctness-proven in earlier rounds R10/R11.)
static __device__ __forceinline__ void bar_lds() {
  asm volatile("s_waitcnt lgkmcnt(0)\n\ts_barrier" ::: "memory");
}

// [rows][64] bf16 tiles, 16B chunks 0..7 (chunk=elem>>3), chunk ^= row&7.
__device__ __forceinline__ int kk_idx(int row, int chunk) {
  return row * 64 + (((chunk ^ (row & 7)) & 7) << 3);
}
// attn V^T tile: [64 d][64 kv] bf16, chunks 0..7 (kv>>3),
// chunk ^= (d&7) ^ ((d>>3)&7)
__device__ __forceinline__ int vv_idx(int d, int chunk) {
  return d * 64 + (((chunk ^ (d & 7) ^ ((d >> 3) & 7)) & 7) << 3);
}

// ---------------------------------------------------------------------------
// Merged fp32 -> bf16 conversion for x, Wqkv, Wproj (outputs contiguous).
__global__ __launch_bounds__(256) void f32_to_bf16_3(
    const float* __restrict__ x, const float* __restrict__ wq,
    const float* __restrict__ wp, unsigned short* __restrict__ outb,
    int n1, int n2, int n3)
{
  const int i = blockIdx.x * 256 + threadIdx.x;
  const float* src; unsigned short* dst; int j;
  if (i < n1)            { src = x;  dst = outb;                        j = i; }
  else if (i < n1 + n2)  { src = wq; dst = outb + (size_t)n1 * 4;       j = i - n1; }
  else if (i < n1+n2+n3) { src = wp; dst = outb + (size_t)(n1+n2) * 4;  j = i - n1 - n2; }
  else return;
  const float4 v = ((const float4*)src)[j];
  const unsigned lo = (unsigned)f2bf(v.x) | ((unsigned)f2bf(v.y) << 16);
  const unsigned hi = (unsigned)f2bf(v.z) | ((unsigned)f2bf(v.w) << 16);
  ((uint2*)dst)[j] = make_uint2(lo, hi);
}

// ---------------------------------------------------------------------------
// C[m][n] = sum_k A[m][k]*B[n][k] + bias[n]; A,B bf16, bias fp32.
// bf16 MFMA 16x16x32, BM=128, BN=FJ*32, BK=64, 4 waves (2x2), 4xFJ frags.
// Staging via global_load_lds (linear LDS dest, pre-swizzled global source).
// ---------------------------------------------------------------------------
template <int FJ, bool OUT_BF16, int MWPE>
__global__ __launch_bounds__(256, MWPE) void gemm_bt_mfma(
    const unsigned short* __restrict__ A, const unsigned short* __restrict__ B,
    const float* __restrict__ bias, void* __restrict__ Cv,
    int M, int N, int K)
{
  __shared__ unsigned short As[128 * 64];
  __shared__ unsigned short Bs[FJ * 32 * 64];

  const int tid  = threadIdx.x;
  const int lane = tid & 63;
  const int wv   = tid >> 6;
  const int wr   = wv >> 1, wc = wv & 1;
  const int l15  = lane & 15, g = lane >> 4;
  const int bn = blockIdx.x, bm = blockIdx.y;

  const int srow = tid >> 3;                      // 0..31 (call adds c*32)
  const int chg  = (tid & 7) ^ (srow & 7);        // pre-swizzled source chunk
  const unsigned short* Ab = A + (size_t)(bm * 128 + srow) * K + chg * 8;
  const unsigned short* Bb = B + (size_t)(bn * (FJ * 32) + srow) * K + chg * 8;

  f32x4 acc[4][FJ];
#pragma unroll
  for (int i = 0; i < 4; ++i)
#pragma unroll
    for (int j = 0; j < FJ; ++j) acc[i][j] = (f32x4){0.f, 0.f, 0.f, 0.f};

  for (int k0 = 0; k0 < K; k0 += 64) {
    __syncthreads();            // prev iter's readers done
#pragma unroll
    for (int c = 0; c < 4; ++c)
      g2lds16(Ab + (size_t)(c * 32) * K + k0, &As[c * 2048 + wv * 512]);
#pragma unroll
    for (int c = 0; c < FJ; ++c)
      g2lds16(Bb + (size_t)(c * 32) * K + k0, &Bs[c * 2048 + wv * 512]);
    __syncthreads();            // implicit vmcnt(0) drains the DMA

#pragma unroll
    for (int kk = 0; kk < 2; ++kk) {
      short8_t af[4], bf[FJ];
#pragma unroll
      for (int i = 0; i < 4; ++i)
        af[i] = *(const short8_t*)&As[kk_idx(wr * 64 + i * 16 + l15, kk * 4 + g)];
#pragma unroll
      for (int j = 0; j < FJ; ++j)
        bf[j] = *(const short8_t*)&Bs[kk_idx(wc * (FJ * 16) + j * 16 + l15, kk * 4 + g)];
#pragma unroll
      for (int i = 0; i < 4; ++i)
#pragma unroll
        for (int j = 0; j < FJ; ++j)
          acc[i][j] = __builtin_amdgcn_mfma_f32_16x16x32_bf16(af[i], bf[j], acc[i][j], 0, 0, 0);
    }
  }

#pragma unroll
  for (int j = 0; j < FJ; ++j) {
    const int col = bn * (FJ * 32) + wc * (FJ * 16) + j * 16 + l15;
    const float bj = bias[col];
#pragma unroll
    for (int i = 0; i < 4; ++i) {
#pragma unroll
      for (int r = 0; r < 4; ++r) {
        const int row = bm * 128 + wr * 64 + i * 16 + g * 4 + r;
        const float v = acc[i][j][r] + bj;
        if (OUT_BF16) ((unsigned short*)Cv)[(size_t)row * N + col] = f2bf(v);
        else          ((float*)Cv)[(size_t)row * N + col] = v;
      }
    }
  }
}

// ---------------------------------------------------------------------------
// Causal flash attention, bf16 MFMA 16x16x32, swapped QK^T, split-KV.
// Block = 512 thr / 8 waves, 64 q-rows: wave -> (qs=wv&3, kvh=wv>>2).
// 128-kv CHUNKED staging: one barrier per 128 kv (2 compute sub-steps,
// separate [64][64] sub-buffers); staging barrier is lgkmcnt-only so the
// register K/V prefetch loads stay in flight across it.
// Fast path (no masks, scale fused into exp) for all chunks below the
// diagonal (block-uniform); single tail chunk runs the masked body.
// Speculative exp with defer-max; kv halves merge per phase in LDS.
// VGPR cliff: must stay <=64 VGPRs (64->68 halves residency, +18us) —
// enforced via __launch_bounds__(512, 8).  grid: 512, XCD-grouped.
// ---------------------------------------------------------------------------
__global__ __launch_bounds__(512, 8) void attn_mfma(
    const unsigned short* __restrict__ qkv, unsigned short* __restrict__ yb)
{
  // K 4x4096 | V 4x4096 | P 8x640   (75776 B total, 2 blocks/CU)
  __shared__ unsigned short SM[37888];
  unsigned short* Ks = SM;
  unsigned short* Vt = SM + 16384;
  unsigned short* Ps = SM + 32768;

  const int tid  = threadIdx.x;
  const int lane = tid & 63;
  const int wv   = tid >> 6;          // 0..7
  const int qs   = wv & 3;            // q-subtile within block
  const int kvh  = wv >> 2;           // kv half (0: kv 0..31, 1: 32..63)
  const int l15  = lane & 15, g = lane >> 4;

  // XCD grouping: bits[2:0]+bit[8:7] pick (b,h) group; bits[6:3] pick x.
  const int nfl = blockIdx.x;
  const int x   = (nfl >> 3) & 15;
  const int grp = (nfl & 7) | ((nfl >> 7) << 3);
  const int h = grp & 15, b = grp >> 4;

  const unsigned short* kbase = qkv + (size_t)(b * TSEQ) * C3 + CDIM + h * HDIM;
  const unsigned short* vbase = kbase + CDIM;
  unsigned short* Pw = &Ps[wv * 640];

  const float SC2 = 0.18033688011112042f;   // log2(e)/8
  const float THR = 11.5415603f;            // 8*log2(e)

  // staging map (512 threads), per 64-row sub-buffer:
  const int skv = tid >> 3, sc = tid & 7;
  const int kwo = kk_idx(skv, sc);
  const int vs = tid >> 4, dh = (tid >> 3) & 1, va = tid & 7;
  int vwo[4];
#pragma unroll
  for (int j = 0; j < 4; ++j)
    vwo[j] = vv_idx(va * 8 + dh * 4 + j, vs >> 2) + ((2 * vs) & 7);

  for (int ph = 0; ph < 2; ++ph) {
    const int qt   = ph ? (31 - x) : x;       // 64-row q-tile id
    const int wq0  = qt * 64 + qs * 16;       // wave's first q row
    const int q_hi = wq0 + 15;
    const int qg   = wq0 + l15;               // this lane's q row
    const int fastc = qt >> 1;                // full-fast 128-chunks

    // Q fragment (B-operand: col=q=l15, k=g*8+j)
    short8_t qf[2];
#pragma unroll
    for (int kk = 0; kk < 2; ++kk)
      qf[kk] = *(const short8_t*)(qkv +
          (size_t)(b * TSEQ + wq0 + l15) * C3 + h * HDIM + kk * 32 + g * 8);

    f32x4 O[4];
#pragma unroll
    for (int n = 0; n < 4; ++n) O[n] = (f32x4){0.f, 0.f, 0.f, 0.f};
    float Mr = 0.0f, Lr = 0.f;          // Mr=0: valid shift; rescale guards it

    // prefetch chunk 0 (128 kv rows) into registers
    const unsigned short* kptr  = kbase + (size_t)skv * C3 + sc * 8;
    const unsigned short* vptr0 = vbase + (size_t)(2 * vs) * C3 + va * 8 + dh * 4;
    short8_t pk0 = *(const short8_t*)(kptr);
    short8_t pk1 = *(const short8_t*)(kptr + (size_t)64 * C3);
    short4_t pv0 = *(const short4_t*)(vptr0);
    short4_t pv1 = *(const short4_t*)(vptr0 + C3);
    short4_t pv2 = *(const short4_t*)(vptr0 + (size_t)64 * C3);
    short4_t pv3 = *(const short4_t*)(vptr0 + (size_t)65 * C3);

    // ---- main loop: 128-chunks fully below the diagonal ----
    for (int c = 0; c < fastc; ++c) {
      const int p2 = (c & 1) << 1;          // buffer pair base (0 or 2)
      {
        unsigned short* K0 = &Ks[p2 * 4096];
        unsigned short* K1 = &Ks[(p2 + 1) * 4096];
        unsigned short* V0 = &Vt[p2 * 4096];
        unsigned short* V1 = &Vt[(p2 + 1) * 4096];
        *(short8_t*)&K0[kwo] = pk0;
        *(short8_t*)&K1[kwo] = pk1;
        const unsigned short* e0 = (const unsigned short*)&pv0;
        const unsigned short* e1 = (const unsigned short*)&pv1;
        const unsigned short* e2 = (const unsigned short*)&pv2;
        const unsigned short* e3 = (const unsigned short*)&pv3;
#pragma unroll
        for (int j = 0; j < 4; ++j) {
          *(unsigned*)&V0[vwo[j]] = (unsigned)e0[j] | ((unsigned)e1[j] << 16);
          *(unsigned*)&V1[vwo[j]] = (unsigned)e2[j] | ((unsigned)e3[j] << 16);
        }
      }
      bar_lds();                // lgkmcnt-only: vm prefetches stay in flight
      // next chunk always exists (c+1 <= fastc = nchunks-1)
      kptr  += (size_t)128 * C3;
      vptr0 += (size_t)128 * C3;
      pk0 = *(const short8_t*)(kptr);
      pk1 = *(const short8_t*)(kptr + (size_t)64 * C3);
      pv0 = *(const short4_t*)(vptr0);
      pv1 = *(const short4_t*)(vptr0 + C3);
      pv2 = *(const short4_t*)(vptr0 + (size_t)64 * C3);
      pv3 = *(const short4_t*)(vptr0 + (size_t)65 * C3);

#pragma unroll
      for (int sub = 0; sub < 2; ++sub) {
        const unsigned short* Kc = &Ks[(p2 + sub) * 4096];
        const unsigned short* Vc = &Vt[(p2 + sub) * 4096];

        // S^T = K Q^T  (D-layout: row(kv)=g*4+r, col(q)=l15)
        f32x4 s[2];
#pragma unroll
        for (int n = 0; n < 2; ++n) s[n] = (f32x4){0.f, 0.f, 0.f, 0.f};
        __builtin_amdgcn_s_setprio(1);
#pragma unroll
        for (int n = 0; n < 2; ++n) {
#pragma unroll
          for (int kk = 0; kk < 2; ++kk) {
            const short8_t kf =
                *(const short8_t*)&Kc[kk_idx(kvh * 32 + n * 16 + l15, kk * 4 + g)];
            s[n] = __builtin_amdgcn_mfma_f32_16x16x32_bf16(kf, qf[kk], s[n], 0, 0, 0);
          }
        }
        __builtin_amdgcn_s_setprio(0);

        // no mask; raw max; scale fused into exp (speculative vs Mr)
        float mt = -3.0e38f, rs = 0.f;
#pragma unroll
        for (int n = 0; n < 2; ++n)
#pragma unroll
          for (int r = 0; r < 4; ++r) mt = fmaxf(mt, s[n][r]);
#pragma unroll
        for (int n = 0; n < 2; ++n)
#pragma unroll
          for (int r = 0; r < 4; ++r) {
            const float p = __builtin_amdgcn_exp2f(fmaf(s[n][r], SC2, -Mr));
            s[n][r] = p;
            rs += p;
          }
        // pack & store P immediately (PV can start; shuffles off critical path)
#pragma unroll
        for (int n = 0; n < 2; ++n) {
          const unsigned u0 = cvtpk_bf16(s[n][0], s[n][1]);
          const unsigned u1 = cvtpk_bf16(s[n][2], s[n][3]);
          *(uint2*)&Pw[l15 * 40 + n * 16 + (g << 2)] = make_uint2(u0, u1);
        }
        mt *= SC2;
        mt = fmaxf(mt, __shfl_xor(mt, 16));
        mt = fmaxf(mt, __shfl_xor(mt, 32));
        if (__any(mt > Mr + THR)) {           // rare: redo with new max
          const float nm = fmaxf(Mr, mt);
          const float al = __builtin_amdgcn_exp2f(Mr - nm);
          Lr *= al;
          rs *= al;
          float alq[4];
#pragma unroll
          for (int r = 0; r < 4; ++r) alq[r] = __shfl(al, (g << 2) + r);
#pragma unroll
          for (int n = 0; n < 4; ++n)
#pragma unroll
            for (int r = 0; r < 4; ++r) O[n][r] *= alq[r];
          Mr = nm;
#pragma unroll
          for (int n = 0; n < 2; ++n) {
#pragma unroll
            for (int r = 0; r < 4; ++r) s[n][r] *= al;
            const unsigned u0 = cvtpk_bf16(s[n][0], s[n][1]);
            const unsigned u1 = cvtpk_bf16(s[n][2], s[n][3]);
            *(uint2*)&Pw[l15 * 40 + n * 16 + (g << 2)] = make_uint2(u0, u1);
          }
        }

        // PV over this wave's 32-kv half
        const short8_t pf = *(const short8_t*)&Pw[l15 * 40 + g * 8];
        __builtin_amdgcn_s_setprio(1);
#pragma unroll
        for (int n = 0; n < 4; ++n) {
          const short8_t vf = *(const short8_t*)&Vc[vv_idx(n * 16 + l15, kvh * 4 + g)];
          O[n] = __builtin_amdgcn_mfma_f32_16x16x32_bf16(pf, vf, O[n], 0, 0, 0);
        }
        __builtin_amdgcn_s_setprio(0);

        rs += __shfl_xor(rs, 16);
        rs += __shfl_xor(rs, 32);
        Lr += rs;
      }
    }

    // ---- tail chunk c = fastc (contains the diagonal); masked body ----
    {
      const int p2 = (fastc & 1) << 1;
      {
        unsigned short* K0 = &Ks[p2 * 4096];
        unsigned short* K1 = &Ks[(p2 + 1) * 4096];
        unsigned short* V0 = &Vt[p2 * 4096];
        unsigned short* V1 = &Vt[(p2 + 1) * 4096];
        *(short8_t*)&K0[kwo] = pk0;
        *(short8_t*)&K1[kwo] = pk1;
        const unsigned short* e0 = (const unsigned short*)&pv0;
        const unsigned short* e1 = (const unsigned short*)&pv1;
        const unsigned short* e2 = (const unsigned short*)&pv2;
        const unsigned short* e3 = (const unsigned short*)&pv3;
#pragma unroll
        for (int j = 0; j < 4; ++j) {
          *(unsigned*)&V0[vwo[j]] = (unsigned)e0[j] | ((unsigned)e1[j] << 16);
          *(unsigned*)&V1[vwo[j]] = (unsigned)e2[j] | ((unsigned)e3[j] << 16);
        }
      }
      bar_lds();

#pragma unroll
      for (int sub = 0; sub < 2; ++sub) {
        const int kvw0 = fastc * 128 + sub * 64 + kvh * 32;
        if (kvw0 > q_hi) continue;            // wave-uniform skip
        const unsigned short* Kc = &Ks[(p2 + sub) * 4096];
        const unsigned short* Vc = &Vt[(p2 + sub) * 4096];
        const int nl = (q_hi - kvw0) >> 4;
        const int nlim = (nl > 1) ? 1 : nl;

        f32x4 s[2];
#pragma unroll
        for (int n = 0; n < 2; ++n) s[n] = (f32x4){0.f, 0.f, 0.f, 0.f};
        __builtin_amdgcn_s_setprio(1);
#pragma unroll
        for (int n = 0; n < 2; ++n) {
          if (n <= nlim) {
#pragma unroll
            for (int kk = 0; kk < 2; ++kk) {
              const short8_t kf =
                  *(const short8_t*)&Kc[kk_idx(kvh * 32 + n * 16 + l15, kk * 4 + g)];
              s[n] = __builtin_amdgcn_mfma_f32_16x16x32_bf16(kf, qf[kk], s[n], 0, 0, 0);
            }
          }
        }
        __builtin_amdgcn_s_setprio(0);

        float mt = -3.0e38f;
#pragma unroll
        for (int n = 0; n < 2; ++n) {
          if (n <= nlim) {
            const int kvb = kvw0 + n * 16 + g * 4;
            const bool needmask = (kvw0 + n * 16 + 15 > wq0);
#pragma unroll
            for (int r = 0; r < 4; ++r) {
              float v = s[n][r] * SC2;
              if (needmask && (kvb + r > qg)) v = -3.0e38f;
              s[n][r] = v;
              mt = fmaxf(mt, v);
            }
          }
        }
        float rs = 0.f;
#pragma unroll
        for (int n = 0; n < 2; ++n) {
          if (n <= nlim) {
#pragma unroll
            for (int r = 0; r < 4; ++r) {
              const float p = __builtin_amdgcn_exp2f(s[n][r] - Mr);
              s[n][r] = p;
              rs += p;
            }
          }
          // n > nlim: s[n] stays 0 -> zero P columns (PV-safe)
        }
#pragma unroll
        for (int n = 0; n < 2; ++n) {
          const unsigned u0 = cvtpk_bf16(s[n][0], s[n][1]);
          const unsigned u1 = cvtpk_bf16(s[n][2], s[n][3]);
          *(uint2*)&Pw[l15 * 40 + n * 16 + (g << 2)] = make_uint2(u0, u1);
        }
        mt = fmaxf(mt, __shfl_xor(mt, 16));
        mt = fmaxf(mt, __shfl_xor(mt, 32));
        if (__any(mt > Mr + THR)) {
          const float nm = fmaxf(Mr, mt);
          const float al = __builtin_amdgcn_exp2f(Mr - nm);
          Lr *= al;
          rs *= al;
          float alq[4];
#pragma unroll
          for (int r = 0; r < 4; ++r) alq[r] = __shfl(al, (g << 2) + r);
#pragma unroll
          for (int n = 0; n < 4; ++n)
#pragma unroll
            for (int r = 0; r < 4; ++r) O[n][r] *= alq[r];
          Mr = nm;
#pragma unroll
          for (int n = 0; n < 2; ++n) {
            if (n <= nlim) {
#pragma unroll
              for (int r = 0; r < 4; ++r) s[n][r] *= al;
            }
            const unsigned u0 = cvtpk_bf16(s[n][0], s[n][1]);
            const unsigned u1 = cvtpk_bf16(s[n][2], s[n][3]);
            *(uint2*)&Pw[l15 * 40 + n * 16 + (g << 2)] = make_uint2(u0, u1);
          }
        }

        const short8_t pf = *(const short8_t*)&Pw[l15 * 40 + g * 8];
        __builtin_amdgcn_s_setprio(1);
#pragma unroll
        for (int n = 0; n < 4; ++n) {
          const short8_t vf = *(const short8_t*)&Vc[vv_idx(n * 16 + l15, kvh * 4 + g)];
          O[n] = __builtin_amdgcn_mfma_f32_16x16x32_bf16(pf, vf, O[n], 0, 0, 0);
        }
        __builtin_amdgcn_s_setprio(0);

        rs += __shfl_xor(rs, 16);
        rs += __shfl_xor(rs, 32);
        Lr += rs;
      }
    }

    // ---- combine kv halves: waves (qs, kvh=0) and (qs, kvh=1) ----
    __syncthreads();                       // all waves done reading K/V LDS
    {
      float* Cb = (float*)SM;              // 4*64*18 floats = 18 KB
      const int slot = (qs * 64 + lane) * 18;
      if (kvh == 1) {
#pragma unroll
        for (int n = 0; n < 4; ++n)
#pragma unroll
          for (int r = 0; r < 4; ++r) Cb[slot + n * 4 + r] = O[n][r];
        Cb[slot + 16] = Mr;
        Cb[slot + 17] = Lr;
      }
    }
    __syncthreads();
    if (kvh == 0) {
      const float* Cb = (const float*)SM;
      const int slot = (qs * 64 + lane) * 18;
      const float m2 = Cb[slot + 16], l2 = Cb[slot + 17];
      const float m  = fmaxf(Mr, m2);
      const float a1 = __builtin_amdgcn_exp2f(Mr - m);
      const float a2 = __builtin_amdgcn_exp2f(m2 - m);
      const float inv = 1.0f / (Lr * a1 + l2 * a2);
      const float fa = a1 * inv, fb = a2 * inv;
      float faq[4], fbq[4];
#pragma unroll
      for (int r = 0; r < 4; ++r) {
        faq[r] = __shfl(fa, (g << 2) + r);
        fbq[r] = __shfl(fb, (g << 2) + r);
      }
#pragma unroll
      for (int n = 0; n < 4; ++n)
#pragma unroll
        for (int r = 0; r < 4; ++r) {
          const float o2 = Cb[slot + n * 4 + r];
          const size_t row = (size_t)(b * TSEQ + wq0 + (g << 2) + r);
          yb[row * CDIM + h * HDIM + n * 16 + l15] =
              f2bf(O[n][r] * faq[r] + o2 * fbq[r]);
        }
    }
    __syncthreads();                       // protect Cb before next staging
  }
}

// ---------------------------------------------------------------------------
extern "C" void kernel_launch(void* const* d_in, const int* in_sizes, int n_in,
                              void* d_out, int out_size, void* d_ws, size_t ws_size,
                              hipStream_t stream)
{
  const float* x     = (const float*)d_in[0];   // [B,T,C] fp32
  const float* Wqkv  = (const float*)d_in[1];   // [3C,C]  fp32
  const float* bqkv  = (const float*)d_in[2];   // [3C]
  const float* Wproj = (const float*)d_in[3];   // [C,C]
  const float* bproj = (const float*)d_in[4];   // [C]
  float* out = (float*)d_out;                   // [B,T,C] fp32

  const int M = BDIM * TSEQ;                    // 4096
  unsigned short* qkv = (unsigned short*)d_ws;          // M x 3C
  unsigned short* yb  = qkv + (size_t)M * C3;           // M x C
  unsigned short* xb  = yb  + (size_t)M * CDIM;         // M x C   (contig with
  unsigned short* wqb = xb  + (size_t)M * CDIM;         // 3C x C   wqb, wpb)
  unsigned short* wpb = wqb + (size_t)C3 * CDIM;        // C x C

  // 0) fp32 -> bf16 pre-conversion (RNE), single merged kernel
  const int n1 = M * CDIM / 4, n2 = C3 * CDIM / 4, n3 = CDIM * CDIM / 4;
  f32_to_bf16_3<<<(n1 + n2 + n3 + 255) / 256, 256, 0, stream>>>(
      x, Wqkv, Wproj, xb, n1, n2, n3);

  // 1) qkv = bf16(x @ Wqkv^T + bqkv)   (BN=128, 768 blocks = 3/CU)
  gemm_bt_mfma<4, true, 3><<<dim3(C3 / 128, M / 128), 256, 0, stream>>>(
      xb, wqb, bqkv, (void*)qkv, M, C3, CDIM);

  // 2) causal attention -> yb (bf16)
  attn_mfma<<<dim3(512, 1, 1), 512, 0, stream>>>(qkv, yb);

  // 3) out = yb @ Wproj^T + bproj (fp32 out)  (BN=64 -> 512 blocks, 2/CU)
  gemm_bt_mfma<2, false, 2><<<dim3(CDIM / 64, M / 128), 256, 0, stream>>>(
      yb, wpb, bproj, (void*)out, M, CDIM, CDIM);
}

// Round 18
// 92.789 us; speedup vs baseline: 1.0694x; 1.0471x over previous
//
#include <hip/hip_runtime.h>
#include <cstdint>

#define BDIM  2
#define TSEQ  2048
#define CDIM  1024
#define NHEAD 16
#define HDIM  64
#define C3    3072

typedef __attribute__((ext_vector_type(8))) short short8_t;
typedef __attribute__((ext_vector_type(4))) short short4_t;
typedef __attribute__((ext_vector_type(4))) float f32x4;

static __device__ __forceinline__ unsigned short f2bf(float f) {
  union { float f; unsigned u; } v; v.f = f;
  unsigned r = v.u + 0x7FFFu + ((v.u >> 16) & 1u);   // RNE
  return (unsigned short)(r >> 16);
}
// pack 2 f32 -> 2 bf16 in one u32 (v_cvt_pk_bf16_f32, RNE)
static __device__ __forceinline__ unsigned cvtpk_bf16(float lo, float hi) {
  unsigned r;
  asm("v_cvt_pk_bf16_f32 %0, %1, %2" : "=v"(r) : "v"(lo), "v"(hi));
  return r;
}
// async global->LDS, 16B per lane. LDS dest = wave-uniform base + lane*16.
static __device__ __forceinline__ void g2lds16(const unsigned short* g,
                                               unsigned short* l) {
  __builtin_amdgcn_global_load_lds(
      (const __attribute__((address_space(1))) void*)g,
      (__attribute__((address_space(3))) void*)l, 16, 0, 0);
}
// lgkmcnt-only barrier (attn staging is ds_write-only; keep vm prefetches
// in flight across the barrier). Correctness-proven R10/R11/R17.
static __device__ __forceinline__ void bar_lds() {
  asm volatile("s_waitcnt lgkmcnt(0)\n\ts_barrier" ::: "memory");
}

// [rows][64] bf16 tiles, 16B chunks 0..7 (chunk=elem>>3), chunk ^= row&7.
__device__ __forceinline__ int kk_idx(int row, int chunk) {
  return row * 64 + (((chunk ^ (row & 7)) & 7) << 3);
}
// attn V^T tile: [64 d][64 kv] bf16, chunks 0..7 (kv>>3),
// chunk ^= (d&7) ^ ((d>>3)&7)
__device__ __forceinline__ int vv_idx(int d, int chunk) {
  return d * 64 + (((chunk ^ (d & 7) ^ ((d >> 3) & 7)) & 7) << 3);
}

// ---------------------------------------------------------------------------
// Merged fp32 -> bf16 conversion for x, Wqkv, Wproj (outputs contiguous).
__global__ __launch_bounds__(256) void f32_to_bf16_3(
    const float* __restrict__ x, const float* __restrict__ wq,
    const float* __restrict__ wp, unsigned short* __restrict__ outb,
    int n1, int n2, int n3)
{
  const int i = blockIdx.x * 256 + threadIdx.x;
  const float* src; unsigned short* dst; int j;
  if (i < n1)            { src = x;  dst = outb;                        j = i; }
  else if (i < n1 + n2)  { src = wq; dst = outb + (size_t)n1 * 4;       j = i - n1; }
  else if (i < n1+n2+n3) { src = wp; dst = outb + (size_t)(n1+n2) * 4;  j = i - n1 - n2; }
  else return;
  const float4 v = ((const float4*)src)[j];
  const unsigned lo = (unsigned)f2bf(v.x) | ((unsigned)f2bf(v.y) << 16);
  const unsigned hi = (unsigned)f2bf(v.z) | ((unsigned)f2bf(v.w) << 16);
  ((uint2*)dst)[j] = make_uint2(lo, hi);
}

// ---------------------------------------------------------------------------
// C[m][n] = sum_k A[m][k]*B[n][k] + bias[n]; A,B bf16, bias fp32.
// bf16 MFMA 16x16x32, BM=128, BN=FJ*32, BK=64, 4 waves (2x2), 4xFJ frags.
// Staging via global_load_lds (linear LDS dest, pre-swizzled global source).
// ---------------------------------------------------------------------------
template <int FJ, bool OUT_BF16, int MWPE>
__global__ __launch_bounds__(256, MWPE) void gemm_bt_mfma(
    const unsigned short* __restrict__ A, const unsigned short* __restrict__ B,
    const float* __restrict__ bias, void* __restrict__ Cv,
    int M, int N, int K)
{
  __shared__ unsigned short As[128 * 64];
  __shared__ unsigned short Bs[FJ * 32 * 64];

  const int tid  = threadIdx.x;
  const int lane = tid & 63;
  const int wv   = tid >> 6;
  const int wr   = wv >> 1, wc = wv & 1;
  const int l15  = lane & 15, g = lane >> 4;
  const int bn = blockIdx.x, bm = blockIdx.y;

  const int srow = tid >> 3;                      // 0..31 (call adds c*32)
  const int chg  = (tid & 7) ^ (srow & 7);        // pre-swizzled source chunk
  const unsigned short* Ab = A + (size_t)(bm * 128 + srow) * K + chg * 8;
  const unsigned short* Bb = B + (size_t)(bn * (FJ * 32) + srow) * K + chg * 8;

  f32x4 acc[4][FJ];
#pragma unroll
  for (int i = 0; i < 4; ++i)
#pragma unroll
    for (int j = 0; j < FJ; ++j) acc[i][j] = (f32x4){0.f, 0.f, 0.f, 0.f};

  for (int k0 = 0; k0 < K; k0 += 64) {
    __syncthreads();            // prev iter's readers done
#pragma unroll
    for (int c = 0; c < 4; ++c)
      g2lds16(Ab + (size_t)(c * 32) * K + k0, &As[c * 2048 + wv * 512]);
#pragma unroll
    for (int c = 0; c < FJ; ++c)
      g2lds16(Bb + (size_t)(c * 32) * K + k0, &Bs[c * 2048 + wv * 512]);
    __syncthreads();            // implicit vmcnt(0) drains the DMA

#pragma unroll
    for (int kk = 0; kk < 2; ++kk) {
      short8_t af[4], bf[FJ];
#pragma unroll
      for (int i = 0; i < 4; ++i)
        af[i] = *(const short8_t*)&As[kk_idx(wr * 64 + i * 16 + l15, kk * 4 + g)];
#pragma unroll
      for (int j = 0; j < FJ; ++j)
        bf[j] = *(const short8_t*)&Bs[kk_idx(wc * (FJ * 16) + j * 16 + l15, kk * 4 + g)];
#pragma unroll
      for (int i = 0; i < 4; ++i)
#pragma unroll
        for (int j = 0; j < FJ; ++j)
          acc[i][j] = __builtin_amdgcn_mfma_f32_16x16x32_bf16(af[i], bf[j], acc[i][j], 0, 0, 0);
    }
  }

#pragma unroll
  for (int j = 0; j < FJ; ++j) {
    const int col = bn * (FJ * 32) + wc * (FJ * 16) + j * 16 + l15;
    const float bj = bias[col];
#pragma unroll
    for (int i = 0; i < 4; ++i) {
#pragma unroll
      for (int r = 0; r < 4; ++r) {
        const int row = bm * 128 + wr * 64 + i * 16 + g * 4 + r;
        const float v = acc[i][j][r] + bj;
        if (OUT_BF16) ((unsigned short*)Cv)[(size_t)row * N + col] = f2bf(v);
        else          ((float*)Cv)[(size_t)row * N + col] = v;
      }
    }
  }
}

// ---------------------------------------------------------------------------
// Causal flash attention, bf16 MFMA 16x16x32, swapped QK^T, split-KV.
// Block = 512 thr / 8 waves, 64 q-rows: wave -> (qs=wv&3, kvh=wv>>2).
// 128-kv CHUNKED staging (one lgkmcnt-only barrier per 128 kv, 2 compute
// sub-steps in separate [64][64] sub-buffers). DS-pipe saturation is the
// measured bottleneck -> all removable ds_swizzle shuffles eliminated:
// max-test is lane-local (true row-max reduce only inside the never-taken
// rescale branch); Lr is a PER-LANE partial sum, cross-lane reduced ONCE
// per phase before the combine (4 fewer DS instrs per wave-step).
// Fast path below diagonal (no masks, scale fused into exp); masked tail.
// VGPR cliff: must stay <=64 VGPRs (64->68 halves residency, +18us) —
// enforced via __launch_bounds__(512, 8).  grid: 512, XCD-grouped.
// ---------------------------------------------------------------------------
__global__ __launch_bounds__(512, 8) void attn_mfma(
    const unsigned short* __restrict__ qkv, unsigned short* __restrict__ yb)
{
  // K 4x4096 | V 4x4096 | P 8x640   (75776 B total, 2 blocks/CU)
  __shared__ unsigned short SM[37888];
  unsigned short* Ks = SM;
  unsigned short* Vt = SM + 16384;
  unsigned short* Ps = SM + 32768;

  const int tid  = threadIdx.x;
  const int lane = tid & 63;
  const int wv   = tid >> 6;          // 0..7
  const int qs   = wv & 3;            // q-subtile within block
  const int kvh  = wv >> 2;           // kv half (0: kv 0..31, 1: 32..63)
  const int l15  = lane & 15, g = lane >> 4;

  // XCD grouping: bits[2:0]+bit[8:7] pick (b,h) group; bits[6:3] pick x.
  const int nfl = blockIdx.x;
  const int x   = (nfl >> 3) & 15;
  const int grp = (nfl & 7) | ((nfl >> 7) << 3);
  const int h = grp & 15, b = grp >> 4;

  const unsigned short* kbase = qkv + (size_t)(b * TSEQ) * C3 + CDIM + h * HDIM;
  const unsigned short* vbase = kbase + CDIM;
  unsigned short* Pw = &Ps[wv * 640];

  const float SC2 = 0.18033688011112042f;   // log2(e)/8
  const float THR = 11.5415603f;            // 8*log2(e)

  // staging map (512 threads), per 64-row sub-buffer:
  const int skv = tid >> 3, sc = tid & 7;
  const int kwo = kk_idx(skv, sc);
  const int vs = tid >> 4, dh = (tid >> 3) & 1, va = tid & 7;
  int vwo[4];
#pragma unroll
  for (int j = 0; j < 4; ++j)
    vwo[j] = vv_idx(va * 8 + dh * 4 + j, vs >> 2) + ((2 * vs) & 7);

  for (int ph = 0; ph < 2; ++ph) {
    const int qt   = ph ? (31 - x) : x;       // 64-row q-tile id
    const int wq0  = qt * 64 + qs * 16;       // wave's first q row
    const int q_hi = wq0 + 15;
    const int qg   = wq0 + l15;               // this lane's q row
    const int fastc = qt >> 1;                // full-fast 128-chunks

    // Q fragment (B-operand: col=q=l15, k=g*8+j)
    short8_t qf[2];
#pragma unroll
    for (int kk = 0; kk < 2; ++kk)
      qf[kk] = *(const short8_t*)(qkv +
          (size_t)(b * TSEQ + wq0 + l15) * C3 + h * HDIM + kk * 32 + g * 8);

    f32x4 O[4];
#pragma unroll
    for (int n = 0; n < 4; ++n) O[n] = (f32x4){0.f, 0.f, 0.f, 0.f};
    float Mr = 0.0f, Lr = 0.f;          // Mr=0 valid shift; Lr = PER-LANE partial

    // prefetch chunk 0 (128 kv rows) into registers
    const unsigned short* kptr  = kbase + (size_t)skv * C3 + sc * 8;
    const unsigned short* vptr0 = vbase + (size_t)(2 * vs) * C3 + va * 8 + dh * 4;
    short8_t pk0 = *(const short8_t*)(kptr);
    short8_t pk1 = *(const short8_t*)(kptr + (size_t)64 * C3);
    short4_t pv0 = *(const short4_t*)(vptr0);
    short4_t pv1 = *(const short4_t*)(vptr0 + C3);
    short4_t pv2 = *(const short4_t*)(vptr0 + (size_t)64 * C3);
    short4_t pv3 = *(const short4_t*)(vptr0 + (size_t)65 * C3);

    // ---- main loop: 128-chunks fully below the diagonal ----
    for (int c = 0; c < fastc; ++c) {
      const int p2 = (c & 1) << 1;          // buffer pair base (0 or 2)
      {
        unsigned short* K0 = &Ks[p2 * 4096];
        unsigned short* K1 = &Ks[(p2 + 1) * 4096];
        unsigned short* V0 = &Vt[p2 * 4096];
        unsigned short* V1 = &Vt[(p2 + 1) * 4096];
        *(short8_t*)&K0[kwo] = pk0;
        *(short8_t*)&K1[kwo] = pk1;
        const unsigned short* e0 = (const unsigned short*)&pv0;
        const unsigned short* e1 = (const unsigned short*)&pv1;
        const unsigned short* e2 = (const unsigned short*)&pv2;
        const unsigned short* e3 = (const unsigned short*)&pv3;
#pragma unroll
        for (int j = 0; j < 4; ++j) {
          *(unsigned*)&V0[vwo[j]] = (unsigned)e0[j] | ((unsigned)e1[j] << 16);
          *(unsigned*)&V1[vwo[j]] = (unsigned)e2[j] | ((unsigned)e3[j] << 16);
        }
      }
      bar_lds();                // lgkmcnt-only: vm prefetches stay in flight
      // next chunk always exists (c+1 <= fastc = nchunks-1)
      kptr  += (size_t)128 * C3;
      vptr0 += (size_t)128 * C3;
      pk0 = *(const short8_t*)(kptr);
      pk1 = *(const short8_t*)(kptr + (size_t)64 * C3);
      pv0 = *(const short4_t*)(vptr0);
      pv1 = *(const short4_t*)(vptr0 + C3);
      pv2 = *(const short4_t*)(vptr0 + (size_t)64 * C3);
      pv3 = *(const short4_t*)(vptr0 + (size_t)65 * C3);

#pragma unroll
      for (int sub = 0; sub < 2; ++sub) {
        const unsigned short* Kc = &Ks[(p2 + sub) * 4096];
        const unsigned short* Vc = &Vt[(p2 + sub) * 4096];

        // S^T = K Q^T  (D-layout: row(kv)=g*4+r, col(q)=l15)
        f32x4 s[2];
#pragma unroll
        for (int n = 0; n < 2; ++n) s[n] = (f32x4){0.f, 0.f, 0.f, 0.f};
        __builtin_amdgcn_s_setprio(1);
#pragma unroll
        for (int n = 0; n < 2; ++n) {
#pragma unroll
          for (int kk = 0; kk < 2; ++kk) {
            const short8_t kf =
                *(const short8_t*)&Kc[kk_idx(kvh * 32 + n * 16 + l15, kk * 4 + g)];
            s[n] = __builtin_amdgcn_mfma_f32_16x16x32_bf16(kf, qf[kk], s[n], 0, 0, 0);
          }
        }
        __builtin_amdgcn_s_setprio(0);

        // no mask; lane-local max; scale fused into exp (speculative vs Mr)
        float mt = -3.0e38f, rs = 0.f;
#pragma unroll
        for (int n = 0; n < 2; ++n)
#pragma unroll
          for (int r = 0; r < 4; ++r) mt = fmaxf(mt, s[n][r]);
#pragma unroll
        for (int n = 0; n < 2; ++n)
#pragma unroll
          for (int r = 0; r < 4; ++r) {
            const float p = __builtin_amdgcn_exp2f(fmaf(s[n][r], SC2, -Mr));
            s[n][r] = p;
            rs += p;
          }
        Lr += rs;               // per-lane partial (reduced once per phase)
        // pack & store P immediately (PV can start)
#pragma unroll
        for (int n = 0; n < 2; ++n) {
          const unsigned u0 = cvtpk_bf16(s[n][0], s[n][1]);
          const unsigned u1 = cvtpk_bf16(s[n][2], s[n][3]);
          *(uint2*)&Pw[l15 * 40 + n * 16 + (g << 2)] = make_uint2(u0, u1);
        }
        mt *= SC2;
        // lane-local test is equivalent under __any; shuffles only if taken
        if (__any(mt > Mr + THR)) {           // rare: redo with true row max
          mt = fmaxf(mt, __shfl_xor(mt, 16));
          mt = fmaxf(mt, __shfl_xor(mt, 32));
          const float nm = fmaxf(Mr, mt);
          const float al = __builtin_amdgcn_exp2f(Mr - nm);
          Lr *= al;             // current rs already folded in
          float alq[4];
#pragma unroll
          for (int r = 0; r < 4; ++r) alq[r] = __shfl(al, (g << 2) + r);
#pragma unroll
          for (int n = 0; n < 4; ++n)
#pragma unroll
            for (int r = 0; r < 4; ++r) O[n][r] *= alq[r];
          Mr = nm;
#pragma unroll
          for (int n = 0; n < 2; ++n) {
#pragma unroll
            for (int r = 0; r < 4; ++r) s[n][r] *= al;
            const unsigned u0 = cvtpk_bf16(s[n][0], s[n][1]);
            const unsigned u1 = cvtpk_bf16(s[n][2], s[n][3]);
            *(uint2*)&Pw[l15 * 40 + n * 16 + (g << 2)] = make_uint2(u0, u1);
          }
        }

        // PV over this wave's 32-kv half
        const short8_t pf = *(const short8_t*)&Pw[l15 * 40 + g * 8];
        __builtin_amdgcn_s_setprio(1);
#pragma unroll
        for (int n = 0; n < 4; ++n) {
          const short8_t vf = *(const short8_t*)&Vc[vv_idx(n * 16 + l15, kvh * 4 + g)];
          O[n] = __builtin_amdgcn_mfma_f32_16x16x32_bf16(pf, vf, O[n], 0, 0, 0);
        }
        __builtin_amdgcn_s_setprio(0);
      }
    }

    // ---- tail chunk c = fastc (contains the diagonal); masked body ----
    {
      const int p2 = (fastc & 1) << 1;
      {
        unsigned short* K0 = &Ks[p2 * 4096];
        unsigned short* K1 = &Ks[(p2 + 1) * 4096];
        unsigned short* V0 = &Vt[p2 * 4096];
        unsigned short* V1 = &Vt[(p2 + 1) * 4096];
        *(short8_t*)&K0[kwo] = pk0;
        *(short8_t*)&K1[kwo] = pk1;
        const unsigned short* e0 = (const unsigned short*)&pv0;
        const unsigned short* e1 = (const unsigned short*)&pv1;
        const unsigned short* e2 = (const unsigned short*)&pv2;
        const unsigned short* e3 = (const unsigned short*)&pv3;
#pragma unroll
        for (int j = 0; j < 4; ++j) {
          *(unsigned*)&V0[vwo[j]] = (unsigned)e0[j] | ((unsigned)e1[j] << 16);
          *(unsigned*)&V1[vwo[j]] = (unsigned)e2[j] | ((unsigned)e3[j] << 16);
        }
      }
      bar_lds();

#pragma unroll
      for (int sub = 0; sub < 2; ++sub) {
        const int kvw0 = fastc * 128 + sub * 64 + kvh * 32;
        if (kvw0 > q_hi) continue;            // wave-uniform skip
        const unsigned short* Kc = &Ks[(p2 + sub) * 4096];
        const unsigned short* Vc = &Vt[(p2 + sub) * 4096];
        const int nl = (q_hi - kvw0) >> 4;
        const int nlim = (nl > 1) ? 1 : nl;

        f32x4 s[2];
#pragma unroll
        for (int n = 0; n < 2; ++n) s[n] = (f32x4){0.f, 0.f, 0.f, 0.f};
        __builtin_amdgcn_s_setprio(1);
#pragma unroll
        for (int n = 0; n < 2; ++n) {
          if (n <= nlim) {
#pragma unroll
            for (int kk = 0; kk < 2; ++kk) {
              const short8_t kf =
                  *(const short8_t*)&Kc[kk_idx(kvh * 32 + n * 16 + l15, kk * 4 + g)];
              s[n] = __builtin_amdgcn_mfma_f32_16x16x32_bf16(kf, qf[kk], s[n], 0, 0, 0);
            }
          }
        }
        __builtin_amdgcn_s_setprio(0);

        float mt = -3.0e38f;
#pragma unroll
        for (int n = 0; n < 2; ++n) {
          if (n <= nlim) {
            const int kvb = kvw0 + n * 16 + g * 4;
            const bool needmask = (kvw0 + n * 16 + 15 > wq0);
#pragma unroll
            for (int r = 0; r < 4; ++r) {
              float v = s[n][r] * SC2;
              if (needmask && (kvb + r > qg)) v = -3.0e38f;
              s[n][r] = v;
              mt = fmaxf(mt, v);
            }
          }
        }
        float rs = 0.f;
#pragma unroll
        for (int n = 0; n < 2; ++n) {
          if (n <= nlim) {
#pragma unroll
            for (int r = 0; r < 4; ++r) {
              const float p = __builtin_amdgcn_exp2f(s[n][r] - Mr);
              s[n][r] = p;
              rs += p;
            }
          }
          // n > nlim: s[n] stays 0 -> zero P columns (PV-safe)
        }
        Lr += rs;               // per-lane partial
#pragma unroll
        for (int n = 0; n < 2; ++n) {
          const unsigned u0 = cvtpk_bf16(s[n][0], s[n][1]);
          const unsigned u1 = cvtpk_bf16(s[n][2], s[n][3]);
          *(uint2*)&Pw[l15 * 40 + n * 16 + (g << 2)] = make_uint2(u0, u1);
        }
        if (__any(mt > Mr + THR)) {
          mt = fmaxf(mt, __shfl_xor(mt, 16));
          mt = fmaxf(mt, __shfl_xor(mt, 32));
          const float nm = fmaxf(Mr, mt);
          const float al = __builtin_amdgcn_exp2f(Mr - nm);
          Lr *= al;
          float alq[4];
#pragma unroll
          for (int r = 0; r < 4; ++r) alq[r] = __shfl(al, (g << 2) + r);
#pragma unroll
          for (int n = 0; n < 4; ++n)
#pragma unroll
            for (int r = 0; r < 4; ++r) O[n][r] *= alq[r];
          Mr = nm;
#pragma unroll
          for (int n = 0; n < 2; ++n) {
            if (n <= nlim) {
#pragma unroll
              for (int r = 0; r < 4; ++r) s[n][r] *= al;
            }
            const unsigned u0 = cvtpk_bf16(s[n][0], s[n][1]);
            const unsigned u1 = cvtpk_bf16(s[n][2], s[n][3]);
            *(uint2*)&Pw[l15 * 40 + n * 16 + (g << 2)] = make_uint2(u0, u1);
          }
        }

        const short8_t pf = *(const short8_t*)&Pw[l15 * 40 + g * 8];
        __builtin_amdgcn_s_setprio(1);
#pragma unroll
        for (int n = 0; n < 4; ++n) {
          const short8_t vf = *(const short8_t*)&Vc[vv_idx(n * 16 + l15, kvh * 4 + g)];
          O[n] = __builtin_amdgcn_mfma_f32_16x16x32_bf16(pf, vf, O[n], 0, 0, 0);
        }
        __builtin_amdgcn_s_setprio(0);
      }
    }

    // finalize row sums: deferred cross-lane reduce, ONCE per phase
    Lr += __shfl_xor(Lr, 16);
    Lr += __shfl_xor(Lr, 32);

    // ---- combine kv halves: waves (qs, kvh=0) and (qs, kvh=1) ----
    __syncthreads();                       // all waves done reading K/V LDS
    {
      float* Cb = (float*)SM;              // 4*64*18 floats = 18 KB
      const int slot = (qs * 64 + lane) * 18;
      if (kvh == 1) {
#pragma unroll
        for (int n = 0; n < 4; ++n)
#pragma unroll
          for (int r = 0; r < 4; ++r) Cb[slot + n * 4 + r] = O[n][r];
        Cb[slot + 16] = Mr;
        Cb[slot + 17] = Lr;
      }
    }
    __syncthreads();
    if (kvh == 0) {
      const float* Cb = (const float*)SM;
      const int slot = (qs * 64 + lane) * 18;
      const float m2 = Cb[slot + 16], l2 = Cb[slot + 17];
      const float m  = fmaxf(Mr, m2);
      const float a1 = __builtin_amdgcn_exp2f(Mr - m);
      const float a2 = __builtin_amdgcn_exp2f(m2 - m);
      const float inv = 1.0f / (Lr * a1 + l2 * a2);
      const float fa = a1 * inv, fb = a2 * inv;
      float faq[4], fbq[4];
#pragma unroll
      for (int r = 0; r < 4; ++r) {
        faq[r] = __shfl(fa, (g << 2) + r);
        fbq[r] = __shfl(fb, (g << 2) + r);
      }
#pragma unroll
      for (int n = 0; n < 4; ++n)
#pragma unroll
        for (int r = 0; r < 4; ++r) {
          const float o2 = Cb[slot + n * 4 + r];
          const size_t row = (size_t)(b * TSEQ + wq0 + (g << 2) + r);
          yb[row * CDIM + h * HDIM + n * 16 + l15] =
              f2bf(O[n][r] * faq[r] + o2 * fbq[r]);
        }
    }
    __syncthreads();                       // protect Cb before next staging
  }
}

// ---------------------------------------------------------------------------
extern "C" void kernel_launch(void* const* d_in, const int* in_sizes, int n_in,
                              void* d_out, int out_size, void* d_ws, size_t ws_size,
                              hipStream_t stream)
{
  const float* x     = (const float*)d_in[0];   // [B,T,C] fp32
  const float* Wqkv  = (const float*)d_in[1];   // [3C,C]  fp32
  const float* bqkv  = (const float*)d_in[2];   // [3C]
  const float* Wproj = (const float*)d_in[3];   // [C,C]
  const float* bproj = (const float*)d_in[4];   // [C]
  float* out = (float*)d_out;                   // [B,T,C] fp32

  const int M = BDIM * TSEQ;                    // 4096
  unsigned short* qkv = (unsigned short*)d_ws;          // M x 3C
  unsigned short* yb  = qkv + (size_t)M * C3;           // M x C
  unsigned short* xb  = yb  + (size_t)M * CDIM;         // M x C   (contig with
  unsigned short* wqb = xb  + (size_t)M * CDIM;         // 3C x C   wqb, wpb)
  unsigned short* wpb = wqb + (size_t)C3 * CDIM;        // C x C

  // 0) fp32 -> bf16 pre-conversion (RNE), single merged kernel
  const int n1 = M * CDIM / 4, n2 = C3 * CDIM / 4, n3 = CDIM * CDIM / 4;
  f32_to_bf16_3<<<(n1 + n2 + n3 + 255) / 256, 256, 0, stream>>>(
      x, Wqkv, Wproj, xb, n1, n2, n3);

  // 1) qkv = bf16(x @ Wqkv^T + bqkv)   (BN=128, 768 blocks = 3/CU)
  gemm_bt_mfma<4, true, 3><<<dim3(C3 / 128, M / 128), 256, 0, stream>>>(
      xb, wqb, bqkv, (void*)qkv, M, C3, CDIM);

  // 2) causal attention -> yb (bf16)
  attn_mfma<<<dim3(512, 1, 1), 512, 0, stream>>>(qkv, yb);

  // 3) out = yb @ Wproj^T + bproj (fp32 out)  (BN=64 -> 512 blocks, 2/CU)
  gemm_bt_mfma<2, false, 2><<<dim3(CDIM / 64, M / 128), 256, 0, stream>>>(
      yb, wpb, bproj, (void*)out, M, CDIM, CDIM);
}

// Round 19
// 89.961 us; speedup vs baseline: 1.1030x; 1.0314x over previous
//
#include <hip/hip_runtime.h>
#include <cstdint>

#define BDIM  2
#define TSEQ  2048
#define CDIM  1024
#define NHEAD 16
#define HDIM  64
#define C3    3072

typedef __attribute__((ext_vector_type(8))) short short8_t;
typedef __attribute__((ext_vector_type(4))) short short4_t;
typedef __attribute__((ext_vector_type(4))) float f32x4;

static __device__ __forceinline__ unsigned short f2bf(float f) {
  union { float f; unsigned u; } v; v.f = f;
  unsigned r = v.u + 0x7FFFu + ((v.u >> 16) & 1u);   // RNE
  return (unsigned short)(r >> 16);
}
// pack 2 f32 -> 2 bf16 in one u32 (v_cvt_pk_bf16_f32, RNE)
static __device__ __forceinline__ unsigned cvtpk_bf16(float lo, float hi) {
  unsigned r;
  asm("v_cvt_pk_bf16_f32 %0, %1, %2" : "=v"(r) : "v"(lo), "v"(hi));
  return r;
}
// async global->LDS, 16B per lane. LDS dest = wave-uniform base + lane*16.
static __device__ __forceinline__ void g2lds16(const unsigned short* g,
                                               unsigned short* l) {
  __builtin_amdgcn_global_load_lds(
      (const __attribute__((address_space(1))) void*)g,
      (__attribute__((address_space(3))) void*)l, 16, 0, 0);
}
// lgkmcnt-only barrier (attn staging is ds_write-only; keep vm prefetches
// in flight across the barrier). Correctness-proven R10/R11/R17/R18.
static __device__ __forceinline__ void bar_lds() {
  asm volatile("s_waitcnt lgkmcnt(0)\n\ts_barrier" ::: "memory");
}

// [rows][64] bf16 tiles, 16B chunks 0..7 (chunk=elem>>3), chunk ^= row&7.
__device__ __forceinline__ int kk_idx(int row, int chunk) {
  return row * 64 + (((chunk ^ (row & 7)) & 7) << 3);
}
// attn V^T tile: [64 d][64 kv] bf16, chunks 0..7 (kv>>3),
// chunk ^= (d&7) ^ ((d>>3)&7)
__device__ __forceinline__ int vv_idx(int d, int chunk) {
  return d * 64 + (((chunk ^ (d & 7) ^ ((d >> 3) & 7)) & 7) << 3);
}

// ---------------------------------------------------------------------------
// Merged fp32 -> bf16 conversion for x, Wqkv, Wproj (outputs contiguous).
__global__ __launch_bounds__(256) void f32_to_bf16_3(
    const float* __restrict__ x, const float* __restrict__ wq,
    const float* __restrict__ wp, unsigned short* __restrict__ outb,
    int n1, int n2, int n3)
{
  const int i = blockIdx.x * 256 + threadIdx.x;
  const float* src; unsigned short* dst; int j;
  if (i < n1)            { src = x;  dst = outb;                        j = i; }
  else if (i < n1 + n2)  { src = wq; dst = outb + (size_t)n1 * 4;       j = i - n1; }
  else if (i < n1+n2+n3) { src = wp; dst = outb + (size_t)(n1+n2) * 4;  j = i - n1 - n2; }
  else return;
  const float4 v = ((const float4*)src)[j];
  const unsigned lo = (unsigned)f2bf(v.x) | ((unsigned)f2bf(v.y) << 16);
  const unsigned hi = (unsigned)f2bf(v.z) | ((unsigned)f2bf(v.w) << 16);
  ((uint2*)dst)[j] = make_uint2(lo, hi);
}

// ---------------------------------------------------------------------------
// C[m][n] = sum_k A[m][k]*B[n][k] + bias[n]; A,B bf16, bias fp32.
// bf16 MFMA 16x16x32, BM=128, BN=FJ*32, BK=64, 4 waves (2x2), 4xFJ frags.
// Staging via global_load_lds (linear LDS dest, pre-swizzled global source).
// ---------------------------------------------------------------------------
template <int FJ, bool OUT_BF16, int MWPE>
__global__ __launch_bounds__(256, MWPE) void gemm_bt_mfma(
    const unsigned short* __restrict__ A, const unsigned short* __restrict__ B,
    const float* __restrict__ bias, void* __restrict__ Cv,
    int M, int N, int K)
{
  __shared__ unsigned short As[128 * 64];
  __shared__ unsigned short Bs[FJ * 32 * 64];

  const int tid  = threadIdx.x;
  const int lane = tid & 63;
  const int wv   = tid >> 6;
  const int wr   = wv >> 1, wc = wv & 1;
  const int l15  = lane & 15, g = lane >> 4;
  const int bn = blockIdx.x, bm = blockIdx.y;

  const int srow = tid >> 3;                      // 0..31 (call adds c*32)
  const int chg  = (tid & 7) ^ (srow & 7);        // pre-swizzled source chunk
  const unsigned short* Ab = A + (size_t)(bm * 128 + srow) * K + chg * 8;
  const unsigned short* Bb = B + (size_t)(bn * (FJ * 32) + srow) * K + chg * 8;

  f32x4 acc[4][FJ];
#pragma unroll
  for (int i = 0; i < 4; ++i)
#pragma unroll
    for (int j = 0; j < FJ; ++j) acc[i][j] = (f32x4){0.f, 0.f, 0.f, 0.f};

  for (int k0 = 0; k0 < K; k0 += 64) {
    __syncthreads();            // prev iter's readers done
#pragma unroll
    for (int c = 0; c < 4; ++c)
      g2lds16(Ab + (size_t)(c * 32) * K + k0, &As[c * 2048 + wv * 512]);
#pragma unroll
    for (int c = 0; c < FJ; ++c)
      g2lds16(Bb + (size_t)(c * 32) * K + k0, &Bs[c * 2048 + wv * 512]);
    __syncthreads();            // implicit vmcnt(0) drains the DMA

#pragma unroll
    for (int kk = 0; kk < 2; ++kk) {
      short8_t af[4], bf[FJ];
#pragma unroll
      for (int i = 0; i < 4; ++i)
        af[i] = *(const short8_t*)&As[kk_idx(wr * 64 + i * 16 + l15, kk * 4 + g)];
#pragma unroll
      for (int j = 0; j < FJ; ++j)
        bf[j] = *(const short8_t*)&Bs[kk_idx(wc * (FJ * 16) + j * 16 + l15, kk * 4 + g)];
#pragma unroll
      for (int i = 0; i < 4; ++i)
#pragma unroll
        for (int j = 0; j < FJ; ++j)
          acc[i][j] = __builtin_amdgcn_mfma_f32_16x16x32_bf16(af[i], bf[j], acc[i][j], 0, 0, 0);
    }
  }

#pragma unroll
  for (int j = 0; j < FJ; ++j) {
    const int col = bn * (FJ * 32) + wc * (FJ * 16) + j * 16 + l15;
    const float bj = bias[col];
#pragma unroll
    for (int i = 0; i < 4; ++i) {
#pragma unroll
      for (int r = 0; r < 4; ++r) {
        const int row = bm * 128 + wr * 64 + i * 16 + g * 4 + r;
        const float v = acc[i][j][r] + bj;
        if (OUT_BF16) ((unsigned short*)Cv)[(size_t)row * N + col] = f2bf(v);
        else          ((float*)Cv)[(size_t)row * N + col] = v;
      }
    }
  }
}

// ---------------------------------------------------------------------------
// Causal flash attention, bf16 MFMA 16x16x32, swapped QK^T, split-KV.
// Block = 512 thr / 8 waves, 64 q-rows: wave -> (qs=wv&3, kvh=wv>>2).
// ZERO-LDS P: the kf A-operand rows are loaded PERMUTED
// (row = 8*(l15>>2) + n*4 + (l15&3)) so the QK^T D-layout lands exactly in
// the PV A-fragment layout (lane (g,l15) holds kv = 8g+n*4+r = g*8+j).
// P is packed in-register via 4x v_cvt_pk_bf16_f32 — the P LDS round-trip
// (4 ds_write_b64 + 1 ds_read_b128 + lgkm wait, every sub-step) is GONE.
// 128-kv chunked staging, lgkmcnt-only barriers; lane-local defer-max;
// per-lane Lr partial reduced once per phase. Masked tail (no nlim: masked
// elements exp to 0, PV-safe). VGPR cliff: <=64 enforced via
// __launch_bounds__(512,8). grid: 512, XCD-grouped.
// ---------------------------------------------------------------------------
__global__ __launch_bounds__(512, 8) void attn_mfma(
    const unsigned short* __restrict__ qkv, unsigned short* __restrict__ yb)
{
  // K 4x4096 | V 4x4096   (65536 B total, 2 blocks/CU)
  __shared__ unsigned short SM[32768];
  unsigned short* Ks = SM;
  unsigned short* Vt = SM + 16384;

  const int tid  = threadIdx.x;
  const int lane = tid & 63;
  const int wv   = tid >> 6;          // 0..7
  const int qs   = wv & 3;            // q-subtile within block
  const int kvh  = wv >> 2;           // kv half (0: kv 0..31, 1: 32..63)
  const int l15  = lane & 15, g = lane >> 4;
  const int sig  = 8 * (l15 >> 2) + (l15 & 3);   // kf row permutation base

  // XCD grouping: bits[2:0]+bit[8:7] pick (b,h) group; bits[6:3] pick x.
  const int nfl = blockIdx.x;
  const int x   = (nfl >> 3) & 15;
  const int grp = (nfl & 7) | ((nfl >> 7) << 3);
  const int h = grp & 15, b = grp >> 4;

  const unsigned short* kbase = qkv + (size_t)(b * TSEQ) * C3 + CDIM + h * HDIM;
  const unsigned short* vbase = kbase + CDIM;

  const float SC2 = 0.18033688011112042f;   // log2(e)/8
  const float THR = 11.5415603f;            // 8*log2(e)

  // staging map (512 threads), per 64-row sub-buffer:
  const int skv = tid >> 3, sc = tid & 7;
  const int kwo = kk_idx(skv, sc);
  const int vs = tid >> 4, dh = (tid >> 3) & 1, va = tid & 7;
  int vwo[4];
#pragma unroll
  for (int j = 0; j < 4; ++j)
    vwo[j] = vv_idx(va * 8 + dh * 4 + j, vs >> 2) + ((2 * vs) & 7);

  for (int ph = 0; ph < 2; ++ph) {
    const int qt   = ph ? (31 - x) : x;       // 64-row q-tile id
    const int wq0  = qt * 64 + qs * 16;       // wave's first q row
    const int q_hi = wq0 + 15;
    const int qg   = wq0 + l15;               // this lane's q row
    const int fastc = qt >> 1;                // full-fast 128-chunks

    // Q fragment (B-operand: col=q=l15, k=g*8+j)
    short8_t qf[2];
#pragma unroll
    for (int kk = 0; kk < 2; ++kk)
      qf[kk] = *(const short8_t*)(qkv +
          (size_t)(b * TSEQ + wq0 + l15) * C3 + h * HDIM + kk * 32 + g * 8);

    f32x4 O[4];
#pragma unroll
    for (int n = 0; n < 4; ++n) O[n] = (f32x4){0.f, 0.f, 0.f, 0.f};
    float Mr = 0.0f, Lr = 0.f;          // Mr=0 valid shift; Lr per-lane partial

    // prefetch chunk 0 (128 kv rows) into registers
    const unsigned short* kptr  = kbase + (size_t)skv * C3 + sc * 8;
    const unsigned short* vptr0 = vbase + (size_t)(2 * vs) * C3 + va * 8 + dh * 4;
    short8_t pk0 = *(const short8_t*)(kptr);
    short8_t pk1 = *(const short8_t*)(kptr + (size_t)64 * C3);
    short4_t pv0 = *(const short4_t*)(vptr0);
    short4_t pv1 = *(const short4_t*)(vptr0 + C3);
    short4_t pv2 = *(const short4_t*)(vptr0 + (size_t)64 * C3);
    short4_t pv3 = *(const short4_t*)(vptr0 + (size_t)65 * C3);

    // ---- main loop: 128-chunks fully below the diagonal ----
    for (int c = 0; c < fastc; ++c) {
      const int p2 = (c & 1) << 1;          // buffer pair base (0 or 2)
      {
        unsigned short* K0 = &Ks[p2 * 4096];
        unsigned short* K1 = &Ks[(p2 + 1) * 4096];
        unsigned short* V0 = &Vt[p2 * 4096];
        unsigned short* V1 = &Vt[(p2 + 1) * 4096];
        *(short8_t*)&K0[kwo] = pk0;
        *(short8_t*)&K1[kwo] = pk1;
        const unsigned short* e0 = (const unsigned short*)&pv0;
        const unsigned short* e1 = (const unsigned short*)&pv1;
        const unsigned short* e2 = (const unsigned short*)&pv2;
        const unsigned short* e3 = (const unsigned short*)&pv3;
#pragma unroll
        for (int j = 0; j < 4; ++j) {
          *(unsigned*)&V0[vwo[j]] = (unsigned)e0[j] | ((unsigned)e1[j] << 16);
          *(unsigned*)&V1[vwo[j]] = (unsigned)e2[j] | ((unsigned)e3[j] << 16);
        }
      }
      bar_lds();                // lgkmcnt-only: vm prefetches stay in flight
      // next chunk always exists (c+1 <= fastc = nchunks-1)
      kptr  += (size_t)128 * C3;
      vptr0 += (size_t)128 * C3;
      pk0 = *(const short8_t*)(kptr);
      pk1 = *(const short8_t*)(kptr + (size_t)64 * C3);
      pv0 = *(const short4_t*)(vptr0);
      pv1 = *(const short4_t*)(vptr0 + C3);
      pv2 = *(const short4_t*)(vptr0 + (size_t)64 * C3);
      pv3 = *(const short4_t*)(vptr0 + (size_t)65 * C3);

#pragma unroll
      for (int sub = 0; sub < 2; ++sub) {
        const unsigned short* Kc = &Ks[(p2 + sub) * 4096];
        const unsigned short* Vc = &Vt[(p2 + sub) * 4096];

        // S^T = K Q^T with PERMUTED kf rows: s[n][r] = S[kv=8g+n*4+r][q=l15]
        f32x4 s[2];
#pragma unroll
        for (int n = 0; n < 2; ++n) s[n] = (f32x4){0.f, 0.f, 0.f, 0.f};
        __builtin_amdgcn_s_setprio(1);
#pragma unroll
        for (int n = 0; n < 2; ++n) {
#pragma unroll
          for (int kk = 0; kk < 2; ++kk) {
            const short8_t kf =
                *(const short8_t*)&Kc[kk_idx(kvh * 32 + sig + n * 4, kk * 4 + g)];
            s[n] = __builtin_amdgcn_mfma_f32_16x16x32_bf16(kf, qf[kk], s[n], 0, 0, 0);
          }
        }
        __builtin_amdgcn_s_setprio(0);

        // no mask; lane-local max; scale fused into exp (speculative vs Mr)
        float mt = -3.0e38f, rs = 0.f;
#pragma unroll
        for (int n = 0; n < 2; ++n)
#pragma unroll
          for (int r = 0; r < 4; ++r) mt = fmaxf(mt, s[n][r]);
#pragma unroll
        for (int n = 0; n < 2; ++n)
#pragma unroll
          for (int r = 0; r < 4; ++r) {
            const float p = __builtin_amdgcn_exp2f(fmaf(s[n][r], SC2, -Mr));
            s[n][r] = p;
            rs += p;
          }
        Lr += rs;               // per-lane partial (reduced once per phase)
        // in-register P pack: pf = A-frag (row=q=l15, k=kv=g*8+j)
        uint4 pu;
        pu.x = cvtpk_bf16(s[0][0], s[0][1]);
        pu.y = cvtpk_bf16(s[0][2], s[0][3]);
        pu.z = cvtpk_bf16(s[1][0], s[1][1]);
        pu.w = cvtpk_bf16(s[1][2], s[1][3]);
        mt *= SC2;
        // lane-local test is equivalent under __any; shuffles only if taken
        if (__any(mt > Mr + THR)) {           // rare: redo with true row max
          mt = fmaxf(mt, __shfl_xor(mt, 16));
          mt = fmaxf(mt, __shfl_xor(mt, 32));
          const float nm = fmaxf(Mr, mt);
          const float al = __builtin_amdgcn_exp2f(Mr - nm);
          Lr *= al;             // current rs already folded in
          float alq[4];
#pragma unroll
          for (int r = 0; r < 4; ++r) alq[r] = __shfl(al, (g << 2) + r);
#pragma unroll
          for (int n = 0; n < 4; ++n)
#pragma unroll
            for (int r = 0; r < 4; ++r) O[n][r] *= alq[r];
          Mr = nm;
#pragma unroll
          for (int n = 0; n < 2; ++n)
#pragma unroll
            for (int r = 0; r < 4; ++r) s[n][r] *= al;
          pu.x = cvtpk_bf16(s[0][0], s[0][1]);
          pu.y = cvtpk_bf16(s[0][2], s[0][3]);
          pu.z = cvtpk_bf16(s[1][0], s[1][1]);
          pu.w = cvtpk_bf16(s[1][2], s[1][3]);
        }
        const short8_t pf = *(const short8_t*)&pu;

        // PV over this wave's 32-kv half
        __builtin_amdgcn_s_setprio(1);
#pragma unroll
        for (int n = 0; n < 4; ++n) {
          const short8_t vf = *(const short8_t*)&Vc[vv_idx(n * 16 + l15, kvh * 4 + g)];
          O[n] = __builtin_amdgcn_mfma_f32_16x16x32_bf16(pf, vf, O[n], 0, 0, 0);
        }
        __builtin_amdgcn_s_setprio(0);
      }
    }

    // ---- tail chunk c = fastc (contains the diagonal); masked body ----
    {
      const int p2 = (fastc & 1) << 1;
      {
        unsigned short* K0 = &Ks[p2 * 4096];
        unsigned short* K1 = &Ks[(p2 + 1) * 4096];
        unsigned short* V0 = &Vt[p2 * 4096];
        unsigned short* V1 = &Vt[(p2 + 1) * 4096];
        *(short8_t*)&K0[kwo] = pk0;
        *(short8_t*)&K1[kwo] = pk1;
        const unsigned short* e0 = (const unsigned short*)&pv0;
        const unsigned short* e1 = (const unsigned short*)&pv1;
        const unsigned short* e2 = (const unsigned short*)&pv2;
        const unsigned short* e3 = (const unsigned short*)&pv3;
#pragma unroll
        for (int j = 0; j < 4; ++j) {
          *(unsigned*)&V0[vwo[j]] = (unsigned)e0[j] | ((unsigned)e1[j] << 16);
          *(unsigned*)&V1[vwo[j]] = (unsigned)e2[j] | ((unsigned)e3[j] << 16);
        }
      }
      bar_lds();

#pragma unroll
      for (int sub = 0; sub < 2; ++sub) {
        const int kvw0 = fastc * 128 + sub * 64 + kvh * 32;
        if (kvw0 > q_hi) continue;            // wave-uniform skip
        const unsigned short* Kc = &Ks[(p2 + sub) * 4096];
        const unsigned short* Vc = &Vt[(p2 + sub) * 4096];

        f32x4 s[2];
#pragma unroll
        for (int n = 0; n < 2; ++n) s[n] = (f32x4){0.f, 0.f, 0.f, 0.f};
        __builtin_amdgcn_s_setprio(1);
#pragma unroll
        for (int n = 0; n < 2; ++n) {
#pragma unroll
          for (int kk = 0; kk < 2; ++kk) {
            const short8_t kf =
                *(const short8_t*)&Kc[kk_idx(kvh * 32 + sig + n * 4, kk * 4 + g)];
            s[n] = __builtin_amdgcn_mfma_f32_16x16x32_bf16(kf, qf[kk], s[n], 0, 0, 0);
          }
        }
        __builtin_amdgcn_s_setprio(0);

        // mask everything above the diagonal: kv = kvw0 + 8g + n*4 + r
        float mt = -3.0e38f, rs = 0.f;
#pragma unroll
        for (int n = 0; n < 2; ++n) {
          const int kvb = kvw0 + 8 * g + n * 4;
#pragma unroll
          for (int r = 0; r < 4; ++r) {
            float v = s[n][r] * SC2;
            if (kvb + r > qg) v = -3.0e38f;
            s[n][r] = v;
            mt = fmaxf(mt, v);
          }
        }
#pragma unroll
        for (int n = 0; n < 2; ++n)
#pragma unroll
          for (int r = 0; r < 4; ++r) {
            const float p = __builtin_amdgcn_exp2f(s[n][r] - Mr);
            s[n][r] = p;   // masked -> exp2(-huge) = 0, PV-safe
            rs += p;
          }
        Lr += rs;               // per-lane partial
        uint4 pu;
        pu.x = cvtpk_bf16(s[0][0], s[0][1]);
        pu.y = cvtpk_bf16(s[0][2], s[0][3]);
        pu.z = cvtpk_bf16(s[1][0], s[1][1]);
        pu.w = cvtpk_bf16(s[1][2], s[1][3]);
        if (__any(mt > Mr + THR)) {
          mt = fmaxf(mt, __shfl_xor(mt, 16));
          mt = fmaxf(mt, __shfl_xor(mt, 32));
          const float nm = fmaxf(Mr, mt);
          const float al = __builtin_amdgcn_exp2f(Mr - nm);
          Lr *= al;
          float alq[4];
#pragma unroll
          for (int r = 0; r < 4; ++r) alq[r] = __shfl(al, (g << 2) + r);
#pragma unroll
          for (int n = 0; n < 4; ++n)
#pragma unroll
            for (int r = 0; r < 4; ++r) O[n][r] *= alq[r];
          Mr = nm;
#pragma unroll
          for (int n = 0; n < 2; ++n)
#pragma unroll
            for (int r = 0; r < 4; ++r) s[n][r] *= al;
          pu.x = cvtpk_bf16(s[0][0], s[0][1]);
          pu.y = cvtpk_bf16(s[0][2], s[0][3]);
          pu.z = cvtpk_bf16(s[1][0], s[1][1]);
          pu.w = cvtpk_bf16(s[1][2], s[1][3]);
        }
        const short8_t pf = *(const short8_t*)&pu;

        __builtin_amdgcn_s_setprio(1);
#pragma unroll
        for (int n = 0; n < 4; ++n) {
          const short8_t vf = *(const short8_t*)&Vc[vv_idx(n * 16 + l15, kvh * 4 + g)];
          O[n] = __builtin_amdgcn_mfma_f32_16x16x32_bf16(pf, vf, O[n], 0, 0, 0);
        }
        __builtin_amdgcn_s_setprio(0);
      }
    }

    // finalize row sums: deferred cross-lane reduce, ONCE per phase
    Lr += __shfl_xor(Lr, 16);
    Lr += __shfl_xor(Lr, 32);

    // ---- combine kv halves: waves (qs, kvh=0) and (qs, kvh=1) ----
    __syncthreads();                       // all waves done reading K/V LDS
    {
      float* Cb = (float*)SM;              // 4*64*18 floats = 18 KB
      const int slot = (qs * 64 + lane) * 18;
      if (kvh == 1) {
#pragma unroll
        for (int n = 0; n < 4; ++n)
#pragma unroll
          for (int r = 0; r < 4; ++r) Cb[slot + n * 4 + r] = O[n][r];
        Cb[slot + 16] = Mr;
        Cb[slot + 17] = Lr;
      }
    }
    __syncthreads();
    if (kvh == 0) {
      const float* Cb = (const float*)SM;
      const int slot = (qs * 64 + lane) * 18;
      const float m2 = Cb[slot + 16], l2 = Cb[slot + 17];
      const float m  = fmaxf(Mr, m2);
      const float a1 = __builtin_amdgcn_exp2f(Mr - m);
      const float a2 = __builtin_amdgcn_exp2f(m2 - m);
      const float inv = 1.0f / (Lr * a1 + l2 * a2);
      const float fa = a1 * inv, fb = a2 * inv;
      float faq[4], fbq[4];
#pragma unroll
      for (int r = 0; r < 4; ++r) {
        faq[r] = __shfl(fa, (g << 2) + r);
        fbq[r] = __shfl(fb, (g << 2) + r);
      }
#pragma unroll
      for (int n = 0; n < 4; ++n)
#pragma unroll
        for (int r = 0; r < 4; ++r) {
          const float o2 = Cb[slot + n * 4 + r];
          const size_t row = (size_t)(b * TSEQ + wq0 + (g << 2) + r);
          yb[row * CDIM + h * HDIM + n * 16 + l15] =
              f2bf(O[n][r] * faq[r] + o2 * fbq[r]);
        }
    }
    __syncthreads();                       // protect Cb before next staging
  }
}

// ---------------------------------------------------------------------------
extern "C" void kernel_launch(void* const* d_in, const int* in_sizes, int n_in,
                              void* d_out, int out_size, void* d_ws, size_t ws_size,
                              hipStream_t stream)
{
  const float* x     = (const float*)d_in[0];   // [B,T,C] fp32
  const float* Wqkv  = (const float*)d_in[1];   // [3C,C]  fp32
  const float* bqkv  = (const float*)d_in[2];   // [3C]
  const float* Wproj = (const float*)d_in[3];   // [C,C]
  const float* bproj = (const float*)d_in[4];   // [C]
  float* out = (float*)d_out;                   // [B,T,C] fp32

  const int M = BDIM * TSEQ;                    // 4096
  unsigned short* qkv = (unsigned short*)d_ws;          // M x 3C
  unsigned short* yb  = qkv + (size_t)M * C3;           // M x C
  unsigned short* xb  = yb  + (size_t)M * CDIM;         // M x C   (contig with
  unsigned short* wqb = xb  + (size_t)M * CDIM;         // 3C x C   wqb, wpb)
  unsigned short* wpb = wqb + (size_t)C3 * CDIM;        // C x C

  // 0) fp32 -> bf16 pre-conversion (RNE), single merged kernel
  const int n1 = M * CDIM / 4, n2 = C3 * CDIM / 4, n3 = CDIM * CDIM / 4;
  f32_to_bf16_3<<<(n1 + n2 + n3 + 255) / 256, 256, 0, stream>>>(
      x, Wqkv, Wproj, xb, n1, n2, n3);

  // 1) qkv = bf16(x @ Wqkv^T + bqkv)   (BN=128, 768 blocks = 3/CU)
  gemm_bt_mfma<4, true, 3><<<dim3(C3 / 128, M / 128), 256, 0, stream>>>(
      xb, wqb, bqkv, (void*)qkv, M, C3, CDIM);

  // 2) causal attention -> yb (bf16)
  attn_mfma<<<dim3(512, 1, 1), 512, 0, stream>>>(qkv, yb);

  // 3) out = yb @ Wproj^T + bproj (fp32 out)  (BN=64 -> 512 blocks, 2/CU)
  gemm_bt_mfma<2, false, 2><<<dim3(CDIM / 64, M / 128), 256, 0, stream>>>(
      yb, wpb, bproj, (void*)out, M, CDIM, CDIM);
}